// Round 2
// baseline (1287.142 us; speedup 1.0000x reference)
//
#include <hip/hip_runtime.h>
#include <hip/hip_bf16.h>
#include <math.h>

#define F_IN 128
#define C1 16
#define C2 8

#define LBITS 7                 // 128 nodes per bucket
#define LOCAL (1 << LBITS)
#define NB_MAX 1024             // supports N up to 131072

// ---------------- utility ----------------
__global__ void zero_int(int* __restrict__ p, int n) {
  int i = blockIdx.x * blockDim.x + threadIdx.x;
  if (i < n) p[i] = 0;
}

// ---------------- two-level bucket sort by dst ----------------
// Phase 0: per-bucket histogram (LDS-aggregated)
__global__ void bucket_hist(const int* __restrict__ dst, int* __restrict__ bcount, int E, int NB) {
  __shared__ int h[NB_MAX];
  for (int i = threadIdx.x; i < NB; i += blockDim.x) h[i] = 0;
  __syncthreads();
  int stride = gridDim.x * blockDim.x;
  for (int e = blockIdx.x * blockDim.x + threadIdx.x; e < E; e += stride)
    atomicAdd(&h[dst[e] >> LBITS], 1);
  __syncthreads();
  for (int i = threadIdx.x; i < NB; i += blockDim.x)
    if (h[i]) atomicAdd(&bcount[i], h[i]);
}

// Phase 0b: exclusive scan over bucket counts (single block, 1024 threads)
__global__ void bucket_scan(const int* __restrict__ bcount, int* __restrict__ bbase,
                            int* __restrict__ bcursor, int NB) {
  __shared__ int sd[NB_MAX];
  int t = threadIdx.x;
  int v = (t < NB) ? bcount[t] : 0;
  sd[t] = v;
  __syncthreads();
  int acc = v;
  for (int off = 1; off < NB_MAX; off <<= 1) {
    int u = (t >= off) ? sd[t - off] : 0;
    __syncthreads();
    acc += u;
    sd[t] = acc;
    __syncthreads();
  }
  if (t < NB) {
    int excl = acc - v;
    bbase[t] = excl;
    bcursor[t] = excl;
    if (t == NB - 1) bbase[NB] = acc;
  }
}

// Phase A: append edges to their bucket region, packed as (src<<LBITS)|(dst&(LOCAL-1))
__global__ void phaseA_scatter(const int* __restrict__ src, const int* __restrict__ dst,
                               int* __restrict__ bcursor, int* __restrict__ packed, int E) {
  int e = blockIdx.x * blockDim.x + threadIdx.x;
  if (e < E) {
    int s = src[e];
    int d = dst[e];
    int b = d >> LBITS;
    int p = atomicAdd(&bcursor[b], 1);
    packed[p] = (s << LBITS) | (d & (LOCAL - 1));
  }
}

// Phase B: one block per bucket — local histogram + scan -> row_ptr, then local scatter -> ssrc
__global__ void phaseB_sort(const int* __restrict__ packed, const int* __restrict__ bbase,
                            int* __restrict__ row_ptr, int* __restrict__ ssrc, int N, int E) {
  __shared__ int h[LOCAL];
  __shared__ int ex[LOCAL];
  int b = blockIdx.x;
  int t = threadIdx.x;
  int beg = bbase[b], end = bbase[b + 1];
  int node0 = b << LBITS;
  if (t < LOCAL) h[t] = 0;
  __syncthreads();
  for (int j = beg + t; j < end; j += blockDim.x) atomicAdd(&h[packed[j] & (LOCAL - 1)], 1);
  __syncthreads();
  if (t == 0) {
    int run = 0;
    for (int i = 0; i < LOCAL; i++) {
      ex[i] = run;
      run += h[i];
    }
  }
  __syncthreads();
  if (t < LOCAL) {
    int node = node0 + t;
    if (node < N) row_ptr[node] = beg + ex[t];
    h[t] = ex[t];  // becomes the local cursor
  }
  if (b == gridDim.x - 1 && t == 0) row_ptr[N] = E;
  __syncthreads();
  for (int j = beg + t; j < end; j += blockDim.x) {
    int v = packed[j];
    int l = v & (LOCAL - 1);
    int p = atomicAdd(&h[l], 1);
    ssrc[beg + p] = v >> LBITS;
  }
}

// ---------------- dense transforms ----------------
// XL = x@Wl, XR = x@Wr, SK = x@Wlin + blin ; x:[N,128], W:[128,16]
__global__ void gemm3_128x16(const float* __restrict__ x,
                             const float* __restrict__ Wl, const float* __restrict__ Wr,
                             const float* __restrict__ Wlin, const float* __restrict__ blin,
                             float* __restrict__ XL, float* __restrict__ XR, float* __restrict__ SK,
                             int N) {
  int gid = blockIdx.x * blockDim.x + threadIdx.x;
  int node = gid >> 4;
  int c = gid & 15;
  if (node >= N) return;
  const float4* xr4 = (const float4*)(x + (size_t)node * F_IN);
  float al = 0.f, ar = 0.f, as_ = 0.f;
#pragma unroll 8
  for (int kk = 0; kk < F_IN / 4; kk++) {
    float4 xv = xr4[kk];
    int k = kk * 4;
    al += xv.x * Wl[(k + 0) * 16 + c] + xv.y * Wl[(k + 1) * 16 + c] +
          xv.z * Wl[(k + 2) * 16 + c] + xv.w * Wl[(k + 3) * 16 + c];
    ar += xv.x * Wr[(k + 0) * 16 + c] + xv.y * Wr[(k + 1) * 16 + c] +
          xv.z * Wr[(k + 2) * 16 + c] + xv.w * Wr[(k + 3) * 16 + c];
    as_ += xv.x * Wlin[(k + 0) * 16 + c] + xv.y * Wlin[(k + 1) * 16 + c] +
           xv.z * Wlin[(k + 2) * 16 + c] + xv.w * Wlin[(k + 3) * 16 + c];
  }
  XL[node * 16 + c] = al;
  XR[node * 16 + c] = ar;
  SK[node * 16 + c] = as_ + blin[c];
}

// XL2 = H@Wl2 etc ; H:[N,16], W:[16,8]
__global__ void gemm3_16x8(const float* __restrict__ Hin,
                           const float* __restrict__ Wl, const float* __restrict__ Wr,
                           const float* __restrict__ Wlin, const float* __restrict__ blin,
                           float* __restrict__ XL, float* __restrict__ XR, float* __restrict__ SK,
                           int N) {
  int gid = blockIdx.x * blockDim.x + threadIdx.x;
  int node = gid >> 3;
  int c = gid & 7;
  if (node >= N) return;
  const float* hrow = Hin + (size_t)node * 16;
  float al = 0.f, ar = 0.f, as_ = 0.f;
#pragma unroll
  for (int k = 0; k < 16; k++) {
    float hv = hrow[k];
    al += hv * Wl[k * 8 + c];
    ar += hv * Wr[k * 8 + c];
    as_ += hv * Wlin[k * 8 + c];
  }
  XL[node * 8 + c] = al;
  XR[node * 8 + c] = ar;
  SK[node * 8 + c] = as_ + blin[c];
}

// ---------------- GAT layer (pull mode over CSR) ----------------
template <int C>
__global__ void gat_layer(const float* __restrict__ XL, const float* __restrict__ XR,
                          const float* __restrict__ SK,
                          const float* __restrict__ att, const float* __restrict__ bias,
                          const float* __restrict__ tp,
                          const int* __restrict__ row_ptr, const int* __restrict__ ssrc,
                          float* __restrict__ H, int N) {
  int gid = blockIdx.x * blockDim.x + threadIdx.x;
  int node = gid / C;
  int c = gid & (C - 1);
  if (node >= N) return;
  float xr = XR[(size_t)node * C + c];
  float attc = att[c];
  float tval = tp[0];
  int beg = row_ptr[node], end = row_ptr[node + 1];

  float S0 = 0.f;
  {
    int j = beg;
    int s = (j < end) ? ssrc[j] : 0;
    for (; j < end; ++j) {
      int snext = (j + 1 < end) ? ssrc[j + 1] : 0;
      float v = XL[(size_t)s * C + c];
      float u = v + xr;
      float e = fmaxf(u, 0.2f * u) * attc;
#pragma unroll
      for (int m = 1; m < C; m <<= 1) e += __shfl_xor(e, m, C);
      S0 += __expf(e);
      s = snext;
    }
  }
  float invS0 = (end > beg) ? (1.0f / S0) : 0.f;

  float S1 = 0.f, S2 = 0.f;
  {
    int j = beg;
    int s = (j < end) ? ssrc[j] : 0;
    for (; j < end; ++j) {
      int snext = (j + 1 < end) ? ssrc[j + 1] : 0;
      float v = XL[(size_t)s * C + c];
      float u = v + xr;
      float e = fmaxf(u, 0.2f * u) * attc;
#pragma unroll
      for (int m = 1; m < C; m <<= 1) e += __shfl_xor(e, m, C);
      float alpha = __expf(e) * invS0;
      float mm = v * alpha;
      float w = __expf(mm * tval);
      S1 += w;
      S2 += w * mm;
      s = snext;
    }
  }
  float gat = (end > beg) ? (S2 / S1) : 0.f;
  float h = gat + bias[c] + SK[(size_t)node * C + c];
  H[(size_t)node * C + c] = fmaxf(h, 0.f);
}

// ---------------- MLP head ----------------
__global__ void head_kernel(const float* __restrict__ H2,
                            const float* __restrict__ W3, const float* __restrict__ b3,
                            const float* __restrict__ W4, const float* __restrict__ b4,
                            const float* __restrict__ W5, const float* __restrict__ b5,
                            const float* __restrict__ Wout, const float* __restrict__ bout,
                            float* __restrict__ out, int N) {
  int i = blockIdx.x * blockDim.x + threadIdx.x;
  if (i >= N) return;
  float h[8];
#pragma unroll
  for (int k = 0; k < 8; k++) h[k] = H2[(size_t)i * 8 + k];
  float s4 = 0.f;
#pragma unroll
  for (int cc = 0; cc < 8; cc++) {
    float z = b3[cc];
#pragma unroll
    for (int k = 0; k < 8; k++) z += h[k] * W3[k * 8 + cc];
    z = fmaxf(z, 0.f);
    s4 += z * W4[cc];
  }
  s4 = fmaxf(s4 + b4[0], 0.f);
  float s5 = fmaxf(s4 * W5[0] + b5[0], 0.f);
  float zo = s5 * Wout[0] + bout[0];
  float ls;
  if (zo >= 0.f)
    ls = -log1pf(expf(-zo));
  else
    ls = zo - log1pf(expf(zo));
  out[i] = ls;
}

extern "C" void kernel_launch(void* const* d_in, const int* in_sizes, int n_in,
                              void* d_out, int out_size, void* d_ws, size_t ws_size,
                              hipStream_t stream) {
  const float* x = (const float*)d_in[0];
  const int* ei = (const int*)d_in[1];
  // d_in[2] = batch (arange(N)) -> pooling is identity, unused
  const float* Wl1 = (const float*)d_in[3];
  const float* Wr1 = (const float*)d_in[4];
  const float* att1 = (const float*)d_in[5];
  const float* b1 = (const float*)d_in[6];
  const float* Wlin1 = (const float*)d_in[7];
  const float* blin1 = (const float*)d_in[8];
  const float* Wl2 = (const float*)d_in[9];
  const float* Wr2 = (const float*)d_in[10];
  const float* att2 = (const float*)d_in[11];
  const float* b2 = (const float*)d_in[12];
  const float* Wlin2 = (const float*)d_in[13];
  const float* blin2 = (const float*)d_in[14];
  const float* t = (const float*)d_in[15];
  const float* W3 = (const float*)d_in[16];
  const float* b3 = (const float*)d_in[17];
  const float* W4 = (const float*)d_in[18];
  const float* b4 = (const float*)d_in[19];
  const float* W5 = (const float*)d_in[20];
  const float* b5 = (const float*)d_in[21];
  const float* Wout = (const float*)d_in[22];
  const float* bout = (const float*)d_in[23];
  float* out = (float*)d_out;

  int N = in_sizes[0] / F_IN;
  int E = in_sizes[1] / 2;
  const int* src = ei;
  const int* dst = ei + E;
  int NB = (N + LOCAL - 1) >> LBITS;  // 782 for N=100000, must be <= NB_MAX

  char* ws = (char*)d_ws;
  size_t off = 0;
  auto alloc = [&](size_t bytes) -> void* {
    void* p = ws + off;
    off = (off + bytes + 255) & ~(size_t)255;
    return p;
  };
  int* bcount = (int*)alloc((size_t)NB * 4);
  int* bbase = (int*)alloc((size_t)(NB + 1) * 4);
  int* bcursor = (int*)alloc((size_t)NB * 4);
  int* packed = (int*)alloc((size_t)E * 4);
  int* row_ptr = (int*)alloc((size_t)(N + 1) * 4);
  int* ssrc = (int*)alloc((size_t)E * 4);
  float* XL1 = (float*)alloc((size_t)N * C1 * 4);
  float* XR1 = (float*)alloc((size_t)N * C1 * 4);
  float* SK1 = (float*)alloc((size_t)N * C1 * 4);
  float* H1 = (float*)alloc((size_t)N * C1 * 4);
  float* XL2 = (float*)alloc((size_t)N * C2 * 4);
  float* XR2 = (float*)alloc((size_t)N * C2 * 4);
  float* SK2 = (float*)alloc((size_t)N * C2 * 4);
  float* H2 = (float*)alloc((size_t)N * C2 * 4);

  hipLaunchKernelGGL(zero_int, dim3((NB + 255) / 256), dim3(256), 0, stream, bcount, NB);
  hipLaunchKernelGGL(bucket_hist, dim3(256), dim3(256), 0, stream, dst, bcount, E, NB);
  hipLaunchKernelGGL(bucket_scan, dim3(1), dim3(NB_MAX), 0, stream, bcount, bbase, bcursor, NB);
  hipLaunchKernelGGL(phaseA_scatter, dim3((E + 255) / 256), dim3(256), 0, stream, src, dst, bcursor,
                     packed, E);
  hipLaunchKernelGGL(phaseB_sort, dim3(NB), dim3(256), 0, stream, packed, bbase, row_ptr, ssrc, N,
                     E);
  hipLaunchKernelGGL(gemm3_128x16, dim3((N * 16 + 255) / 256), dim3(256), 0, stream, x, Wl1, Wr1,
                     Wlin1, blin1, XL1, XR1, SK1, N);
  hipLaunchKernelGGL((gat_layer<16>), dim3((N * 16 + 255) / 256), dim3(256), 0, stream, XL1, XR1,
                     SK1, att1, b1, t, row_ptr, ssrc, H1, N);
  hipLaunchKernelGGL(gemm3_16x8, dim3((N * 8 + 255) / 256), dim3(256), 0, stream, H1, Wl2, Wr2,
                     Wlin2, blin2, XL2, XR2, SK2, N);
  hipLaunchKernelGGL((gat_layer<8>), dim3((N * 8 + 255) / 256), dim3(256), 0, stream, XL2, XR2, SK2,
                     att2, b2, t, row_ptr, ssrc, H2, N);
  hipLaunchKernelGGL(head_kernel, dim3((N + 255) / 256), dim3(256), 0, stream, H2, W3, b3, W4, b4,
                     W5, b5, Wout, bout, out, N);
}

// Round 3
// 582.676 us; speedup vs baseline: 2.2090x; 2.2090x over previous
//
#include <hip/hip_runtime.h>
#include <hip/hip_bf16.h>
#include <math.h>

#define F_IN 128
#define C1 16
#define C2 8

#define LBITS 8                 // 256 nodes per bucket
#define LOCAL (1 << LBITS)
#define NB_MAX 512              // supports N up to 131072
#define ITEMS 16                // edges per thread in phase A

// ---------------- utility ----------------
__global__ void zero_int(int* __restrict__ p, int n) {
  int i = blockIdx.x * blockDim.x + threadIdx.x;
  if (i < n) p[i] = 0;
}

// ---------------- two-level bucket sort by dst ----------------
// Phase 0: per-bucket histogram (LDS-aggregated)
__global__ void bucket_hist(const int* __restrict__ dst, int* __restrict__ bcount, int E, int NB) {
  __shared__ int h[NB_MAX];
  for (int i = threadIdx.x; i < NB; i += blockDim.x) h[i] = 0;
  __syncthreads();
  int stride = gridDim.x * blockDim.x;
  for (int e = blockIdx.x * blockDim.x + threadIdx.x; e < E; e += stride)
    atomicAdd(&h[dst[e] >> LBITS], 1);
  __syncthreads();
  for (int i = threadIdx.x; i < NB; i += blockDim.x)
    if (h[i]) atomicAdd(&bcount[i], h[i]);
}

// Phase 0b: exclusive scan over bucket counts (single block)
__global__ void bucket_scan(const int* __restrict__ bcount, int* __restrict__ bbase,
                            int* __restrict__ bcursor, int NB) {
  __shared__ int sd[NB_MAX];
  int t = threadIdx.x;
  int v = (t < NB) ? bcount[t] : 0;
  sd[t] = v;
  __syncthreads();
  int acc = v;
  for (int off = 1; off < NB_MAX; off <<= 1) {
    int u = (t >= off) ? sd[t - off] : 0;
    __syncthreads();
    acc += u;
    sd[t] = acc;
    __syncthreads();
  }
  if (t < NB) {
    int excl = acc - v;
    bbase[t] = excl;
    bcursor[t] = excl;
    if (t == NB - 1) bbase[NB] = acc;
  }
}

// Phase A: LDS-aggregated bucket append. One global atomic per (block,bucket);
// per-edge positions come from LDS cursor atomics (global-positioned).
__global__ void phaseA_lds(const int* __restrict__ src, const int* __restrict__ dst,
                           int* __restrict__ bcursor, int* __restrict__ packed, int E, int NB) {
  __shared__ int hist[NB_MAX];
  __shared__ int cur[NB_MAX];
  for (int i = threadIdx.x; i < NB; i += blockDim.x) hist[i] = 0;
  __syncthreads();
  int base = blockIdx.x * blockDim.x * ITEMS;
  int vals[ITEMS];
  int bkt[ITEMS];
#pragma unroll
  for (int k = 0; k < ITEMS; k++) {
    int e = base + k * blockDim.x + threadIdx.x;
    if (e < E) {
      int s = src[e];
      int d = dst[e];
      bkt[k] = d >> LBITS;
      vals[k] = (s << LBITS) | (d & (LOCAL - 1));
      atomicAdd(&hist[bkt[k]], 1);
    } else {
      bkt[k] = -1;
    }
  }
  __syncthreads();
  for (int i = threadIdx.x; i < NB; i += blockDim.x) {
    int c = hist[i];
    cur[i] = c ? atomicAdd(&bcursor[i], c) : 0;
  }
  __syncthreads();
#pragma unroll
  for (int k = 0; k < ITEMS; k++) {
    if (bkt[k] >= 0) {
      int p = atomicAdd(&cur[bkt[k]], 1);
      packed[p] = vals[k];
    }
  }
}

// Phase B: one block (256 thr) per bucket — LDS histogram + parallel scan -> row_ptr,
// then local scatter -> ssrc within the bucket's contiguous output window.
__global__ void phaseB_sort(const int* __restrict__ packed, const int* __restrict__ bbase,
                            int* __restrict__ row_ptr, int* __restrict__ ssrc, int N, int E) {
  __shared__ int h[LOCAL];
  __shared__ int sd[LOCAL];
  int b = blockIdx.x;
  int t = threadIdx.x;  // blockDim.x == LOCAL == 256
  int beg = bbase[b], end = bbase[b + 1];
  int node0 = b << LBITS;
  h[t] = 0;
  __syncthreads();
  for (int j = beg + t; j < end; j += blockDim.x) atomicAdd(&h[packed[j] & (LOCAL - 1)], 1);
  __syncthreads();
  int cnt = h[t];
  sd[t] = cnt;
  __syncthreads();
  int acc = cnt;
  for (int off = 1; off < LOCAL; off <<= 1) {
    int u = (t >= off) ? sd[t - off] : 0;
    __syncthreads();
    acc += u;
    sd[t] = acc;
    __syncthreads();
  }
  int myex = acc - cnt;  // exclusive prefix within bucket
  int node = node0 + t;
  if (node < N) row_ptr[node] = beg + myex;
  if (node == N) row_ptr[N] = E;  // only when N % LOCAL == 0 edge case
  h[t] = beg + myex;  // global-positioned cursor
  if (b == gridDim.x - 1 && t == 0) row_ptr[N] = E;
  __syncthreads();
  for (int j = beg + t; j < end; j += blockDim.x) {
    int v = packed[j];
    int p = atomicAdd(&h[v & (LOCAL - 1)], 1);
    ssrc[p] = v >> LBITS;
  }
}

// ---------------- dense transforms ----------------
// XL = x@Wl, XR = x@Wr, SK = x@Wlin + blin ; x:[N,128], W:[128,16]
__global__ void gemm3_128x16(const float* __restrict__ x,
                             const float* __restrict__ Wl, const float* __restrict__ Wr,
                             const float* __restrict__ Wlin, const float* __restrict__ blin,
                             float* __restrict__ XL, float* __restrict__ XR, float* __restrict__ SK,
                             int N) {
  int gid = blockIdx.x * blockDim.x + threadIdx.x;
  int node = gid >> 4;
  int c = gid & 15;
  if (node >= N) return;
  const float4* xr4 = (const float4*)(x + (size_t)node * F_IN);
  float al = 0.f, ar = 0.f, as_ = 0.f;
#pragma unroll 8
  for (int kk = 0; kk < F_IN / 4; kk++) {
    float4 xv = xr4[kk];
    int k = kk * 4;
    al += xv.x * Wl[(k + 0) * 16 + c] + xv.y * Wl[(k + 1) * 16 + c] +
          xv.z * Wl[(k + 2) * 16 + c] + xv.w * Wl[(k + 3) * 16 + c];
    ar += xv.x * Wr[(k + 0) * 16 + c] + xv.y * Wr[(k + 1) * 16 + c] +
          xv.z * Wr[(k + 2) * 16 + c] + xv.w * Wr[(k + 3) * 16 + c];
    as_ += xv.x * Wlin[(k + 0) * 16 + c] + xv.y * Wlin[(k + 1) * 16 + c] +
           xv.z * Wlin[(k + 2) * 16 + c] + xv.w * Wlin[(k + 3) * 16 + c];
  }
  XL[node * 16 + c] = al;
  XR[node * 16 + c] = ar;
  SK[node * 16 + c] = as_ + blin[c];
}

// XL2 = H@Wl2 etc ; H:[N,16], W:[16,8]
__global__ void gemm3_16x8(const float* __restrict__ Hin,
                           const float* __restrict__ Wl, const float* __restrict__ Wr,
                           const float* __restrict__ Wlin, const float* __restrict__ blin,
                           float* __restrict__ XL, float* __restrict__ XR, float* __restrict__ SK,
                           int N) {
  int gid = blockIdx.x * blockDim.x + threadIdx.x;
  int node = gid >> 3;
  int c = gid & 7;
  if (node >= N) return;
  const float* hrow = Hin + (size_t)node * 16;
  float al = 0.f, ar = 0.f, as_ = 0.f;
#pragma unroll
  for (int k = 0; k < 16; k++) {
    float hv = hrow[k];
    al += hv * Wl[k * 8 + c];
    ar += hv * Wr[k * 8 + c];
    as_ += hv * Wlin[k * 8 + c];
  }
  XL[node * 8 + c] = al;
  XR[node * 8 + c] = ar;
  SK[node * 8 + c] = as_ + blin[c];
}

// ---------------- GAT layer (pull mode over CSR) ----------------
template <int C>
__global__ void gat_layer(const float* __restrict__ XL, const float* __restrict__ XR,
                          const float* __restrict__ SK,
                          const float* __restrict__ att, const float* __restrict__ bias,
                          const float* __restrict__ tp,
                          const int* __restrict__ row_ptr, const int* __restrict__ ssrc,
                          float* __restrict__ H, int N) {
  int gid = blockIdx.x * blockDim.x + threadIdx.x;
  int node = gid / C;
  int c = gid & (C - 1);
  if (node >= N) return;
  float xr = XR[(size_t)node * C + c];
  float attc = att[c];
  float tval = tp[0];
  int beg = row_ptr[node], end = row_ptr[node + 1];

  float S0 = 0.f;
  {
    int j = beg;
    int s = (j < end) ? ssrc[j] : 0;
    for (; j < end; ++j) {
      int snext = (j + 1 < end) ? ssrc[j + 1] : 0;
      float v = XL[(size_t)s * C + c];
      float u = v + xr;
      float e = fmaxf(u, 0.2f * u) * attc;
#pragma unroll
      for (int m = 1; m < C; m <<= 1) e += __shfl_xor(e, m, C);
      S0 += __expf(e);
      s = snext;
    }
  }
  float invS0 = (end > beg) ? (1.0f / S0) : 0.f;

  float S1 = 0.f, S2 = 0.f;
  {
    int j = beg;
    int s = (j < end) ? ssrc[j] : 0;
    for (; j < end; ++j) {
      int snext = (j + 1 < end) ? ssrc[j + 1] : 0;
      float v = XL[(size_t)s * C + c];
      float u = v + xr;
      float e = fmaxf(u, 0.2f * u) * attc;
#pragma unroll
      for (int m = 1; m < C; m <<= 1) e += __shfl_xor(e, m, C);
      float alpha = __expf(e) * invS0;
      float mm = v * alpha;
      float w = __expf(mm * tval);
      S1 += w;
      S2 += w * mm;
      s = snext;
    }
  }
  float gat = (end > beg) ? (S2 / S1) : 0.f;
  float h = gat + bias[c] + SK[(size_t)node * C + c];
  H[(size_t)node * C + c] = fmaxf(h, 0.f);
}

// ---------------- MLP head ----------------
__global__ void head_kernel(const float* __restrict__ H2,
                            const float* __restrict__ W3, const float* __restrict__ b3,
                            const float* __restrict__ W4, const float* __restrict__ b4,
                            const float* __restrict__ W5, const float* __restrict__ b5,
                            const float* __restrict__ Wout, const float* __restrict__ bout,
                            float* __restrict__ out, int N) {
  int i = blockIdx.x * blockDim.x + threadIdx.x;
  if (i >= N) return;
  float h[8];
#pragma unroll
  for (int k = 0; k < 8; k++) h[k] = H2[(size_t)i * 8 + k];
  float s4 = 0.f;
#pragma unroll
  for (int cc = 0; cc < 8; cc++) {
    float z = b3[cc];
#pragma unroll
    for (int k = 0; k < 8; k++) z += h[k] * W3[k * 8 + cc];
    z = fmaxf(z, 0.f);
    s4 += z * W4[cc];
  }
  s4 = fmaxf(s4 + b4[0], 0.f);
  float s5 = fmaxf(s4 * W5[0] + b5[0], 0.f);
  float zo = s5 * Wout[0] + bout[0];
  float ls;
  if (zo >= 0.f)
    ls = -log1pf(expf(-zo));
  else
    ls = zo - log1pf(expf(zo));
  out[i] = ls;
}

extern "C" void kernel_launch(void* const* d_in, const int* in_sizes, int n_in,
                              void* d_out, int out_size, void* d_ws, size_t ws_size,
                              hipStream_t stream) {
  const float* x = (const float*)d_in[0];
  const int* ei = (const int*)d_in[1];
  // d_in[2] = batch (arange(N)) -> pooling is identity, unused
  const float* Wl1 = (const float*)d_in[3];
  const float* Wr1 = (const float*)d_in[4];
  const float* att1 = (const float*)d_in[5];
  const float* b1 = (const float*)d_in[6];
  const float* Wlin1 = (const float*)d_in[7];
  const float* blin1 = (const float*)d_in[8];
  const float* Wl2 = (const float*)d_in[9];
  const float* Wr2 = (const float*)d_in[10];
  const float* att2 = (const float*)d_in[11];
  const float* b2 = (const float*)d_in[12];
  const float* Wlin2 = (const float*)d_in[13];
  const float* blin2 = (const float*)d_in[14];
  const float* t = (const float*)d_in[15];
  const float* W3 = (const float*)d_in[16];
  const float* b3 = (const float*)d_in[17];
  const float* W4 = (const float*)d_in[18];
  const float* b4 = (const float*)d_in[19];
  const float* W5 = (const float*)d_in[20];
  const float* b5 = (const float*)d_in[21];
  const float* Wout = (const float*)d_in[22];
  const float* bout = (const float*)d_in[23];
  float* out = (float*)d_out;

  int N = in_sizes[0] / F_IN;
  int E = in_sizes[1] / 2;
  const int* src = ei;
  const int* dst = ei + E;
  int NB = (N + LOCAL - 1) >> LBITS;  // 391 for N=100000, must be <= NB_MAX

  char* ws = (char*)d_ws;
  size_t off = 0;
  auto alloc = [&](size_t bytes) -> void* {
    void* p = ws + off;
    off = (off + bytes + 255) & ~(size_t)255;
    return p;
  };
  int* bcount = (int*)alloc((size_t)NB * 4);
  int* bbase = (int*)alloc((size_t)(NB + 1) * 4);
  int* bcursor = (int*)alloc((size_t)NB * 4);
  int* packed = (int*)alloc((size_t)E * 4);
  int* row_ptr = (int*)alloc((size_t)(N + 1) * 4);
  int* ssrc = (int*)alloc((size_t)E * 4);
  float* XL1 = (float*)alloc((size_t)N * C1 * 4);
  float* XR1 = (float*)alloc((size_t)N * C1 * 4);
  float* SK1 = (float*)alloc((size_t)N * C1 * 4);
  float* H1 = (float*)alloc((size_t)N * C1 * 4);
  float* XL2 = (float*)alloc((size_t)N * C2 * 4);
  float* XR2 = (float*)alloc((size_t)N * C2 * 4);
  float* SK2 = (float*)alloc((size_t)N * C2 * 4);
  float* H2 = (float*)alloc((size_t)N * C2 * 4);

  int nblkA = (E + 256 * ITEMS - 1) / (256 * ITEMS);  // 782

  hipLaunchKernelGGL(zero_int, dim3((NB + 255) / 256), dim3(256), 0, stream, bcount, NB);
  hipLaunchKernelGGL(bucket_hist, dim3(512), dim3(256), 0, stream, dst, bcount, E, NB);
  hipLaunchKernelGGL(bucket_scan, dim3(1), dim3(NB_MAX), 0, stream, bcount, bbase, bcursor, NB);
  hipLaunchKernelGGL(phaseA_lds, dim3(nblkA), dim3(256), 0, stream, src, dst, bcursor, packed, E,
                     NB);
  hipLaunchKernelGGL(phaseB_sort, dim3(NB), dim3(LOCAL), 0, stream, packed, bbase, row_ptr, ssrc, N,
                     E);
  hipLaunchKernelGGL(gemm3_128x16, dim3((N * 16 + 255) / 256), dim3(256), 0, stream, x, Wl1, Wr1,
                     Wlin1, blin1, XL1, XR1, SK1, N);
  hipLaunchKernelGGL((gat_layer<16>), dim3((N * 16 + 255) / 256), dim3(256), 0, stream, XL1, XR1,
                     SK1, att1, b1, t, row_ptr, ssrc, H1, N);
  hipLaunchKernelGGL(gemm3_16x8, dim3((N * 8 + 255) / 256), dim3(256), 0, stream, H1, Wl2, Wr2,
                     Wlin2, blin2, XL2, XR2, SK2, N);
  hipLaunchKernelGGL((gat_layer<8>), dim3((N * 8 + 255) / 256), dim3(256), 0, stream, XL2, XR2, SK2,
                     att2, b2, t, row_ptr, ssrc, H2, N);
  hipLaunchKernelGGL(head_kernel, dim3((N + 255) / 256), dim3(256), 0, stream, H2, W3, b3, W4, b4,
                     W5, b5, Wout, bout, out, N);
}

// Round 4
// 567.018 us; speedup vs baseline: 2.2700x; 1.0276x over previous
//
#include <hip/hip_runtime.h>
#include <hip/hip_bf16.h>
#include <math.h>

#define F_IN 128
#define C1 16
#define C2 8

#define LBITS 8                 // 256 nodes per bucket
#define LOCAL (1 << LBITS)
#define NB_MAX 512              // supports N up to 131072
#define ITEMS 16                // edges per thread in phase A

// ---------------- utility ----------------
__global__ void zero_int(int* __restrict__ p, int n) {
  int i = blockIdx.x * blockDim.x + threadIdx.x;
  if (i < n) p[i] = 0;
}

// ---------------- two-level bucket sort by dst ----------------
__global__ void bucket_hist(const int* __restrict__ dst, int* __restrict__ bcount, int E, int NB) {
  __shared__ int h[NB_MAX];
  for (int i = threadIdx.x; i < NB; i += blockDim.x) h[i] = 0;
  __syncthreads();
  int stride = gridDim.x * blockDim.x;
  for (int e = blockIdx.x * blockDim.x + threadIdx.x; e < E; e += stride)
    atomicAdd(&h[dst[e] >> LBITS], 1);
  __syncthreads();
  for (int i = threadIdx.x; i < NB; i += blockDim.x)
    if (h[i]) atomicAdd(&bcount[i], h[i]);
}

__global__ void bucket_scan(const int* __restrict__ bcount, int* __restrict__ bbase,
                            int* __restrict__ bcursor, int NB) {
  __shared__ int sd[NB_MAX];
  int t = threadIdx.x;
  int v = (t < NB) ? bcount[t] : 0;
  sd[t] = v;
  __syncthreads();
  int acc = v;
  for (int off = 1; off < NB_MAX; off <<= 1) {
    int u = (t >= off) ? sd[t - off] : 0;
    __syncthreads();
    acc += u;
    sd[t] = acc;
    __syncthreads();
  }
  if (t < NB) {
    int excl = acc - v;
    bbase[t] = excl;
    bcursor[t] = excl;
    if (t == NB - 1) bbase[NB] = acc;
  }
}

__global__ void phaseA_lds(const int* __restrict__ src, const int* __restrict__ dst,
                           int* __restrict__ bcursor, int* __restrict__ packed, int E, int NB) {
  __shared__ int hist[NB_MAX];
  __shared__ int cur[NB_MAX];
  for (int i = threadIdx.x; i < NB; i += blockDim.x) hist[i] = 0;
  __syncthreads();
  int base = blockIdx.x * blockDim.x * ITEMS;
  int vals[ITEMS];
  int bkt[ITEMS];
#pragma unroll
  for (int k = 0; k < ITEMS; k++) {
    int e = base + k * blockDim.x + threadIdx.x;
    if (e < E) {
      int s = src[e];
      int d = dst[e];
      bkt[k] = d >> LBITS;
      vals[k] = (s << LBITS) | (d & (LOCAL - 1));
      atomicAdd(&hist[bkt[k]], 1);
    } else {
      bkt[k] = -1;
    }
  }
  __syncthreads();
  for (int i = threadIdx.x; i < NB; i += blockDim.x) {
    int c = hist[i];
    cur[i] = c ? atomicAdd(&bcursor[i], c) : 0;
  }
  __syncthreads();
#pragma unroll
  for (int k = 0; k < ITEMS; k++) {
    if (bkt[k] >= 0) {
      int p = atomicAdd(&cur[bkt[k]], 1);
      packed[p] = vals[k];
    }
  }
}

__global__ void phaseB_sort(const int* __restrict__ packed, const int* __restrict__ bbase,
                            int* __restrict__ row_ptr, int* __restrict__ ssrc, int N, int E) {
  __shared__ int h[LOCAL];
  __shared__ int sd[LOCAL];
  int b = blockIdx.x;
  int t = threadIdx.x;  // blockDim.x == LOCAL == 256
  int beg = bbase[b], end = bbase[b + 1];
  int node0 = b << LBITS;
  h[t] = 0;
  __syncthreads();
  for (int j = beg + t; j < end; j += blockDim.x) atomicAdd(&h[packed[j] & (LOCAL - 1)], 1);
  __syncthreads();
  int cnt = h[t];
  sd[t] = cnt;
  __syncthreads();
  int acc = cnt;
  for (int off = 1; off < LOCAL; off <<= 1) {
    int u = (t >= off) ? sd[t - off] : 0;
    __syncthreads();
    acc += u;
    sd[t] = acc;
    __syncthreads();
  }
  int myex = acc - cnt;
  int node = node0 + t;
  if (node < N) row_ptr[node] = beg + myex;
  h[t] = beg + myex;
  if (b == gridDim.x - 1 && t == 0) row_ptr[N] = E;
  __syncthreads();
  for (int j = beg + t; j < end; j += blockDim.x) {
    int v = packed[j];
    int p = atomicAdd(&h[v & (LOCAL - 1)], 1);
    ssrc[p] = v >> LBITS;
  }
}

// ---------------- dense transforms ----------------
// XL (bf16) = x@Wl, XR = x@Wr, SK = x@Wlin + blin ; x:[N,128], W:[128,16]
__global__ void gemm3_128x16(const float* __restrict__ x,
                             const float* __restrict__ Wl, const float* __restrict__ Wr,
                             const float* __restrict__ Wlin, const float* __restrict__ blin,
                             __hip_bfloat16* __restrict__ XLh, float* __restrict__ XR,
                             float* __restrict__ SK, int N) {
  int gid = blockIdx.x * blockDim.x + threadIdx.x;
  int node = gid >> 4;
  int c = gid & 15;
  if (node >= N) return;
  const float4* xr4 = (const float4*)(x + (size_t)node * F_IN);
  float al = 0.f, ar = 0.f, as_ = 0.f;
#pragma unroll 8
  for (int kk = 0; kk < F_IN / 4; kk++) {
    float4 xv = xr4[kk];
    int k = kk * 4;
    al += xv.x * Wl[(k + 0) * 16 + c] + xv.y * Wl[(k + 1) * 16 + c] +
          xv.z * Wl[(k + 2) * 16 + c] + xv.w * Wl[(k + 3) * 16 + c];
    ar += xv.x * Wr[(k + 0) * 16 + c] + xv.y * Wr[(k + 1) * 16 + c] +
          xv.z * Wr[(k + 2) * 16 + c] + xv.w * Wr[(k + 3) * 16 + c];
    as_ += xv.x * Wlin[(k + 0) * 16 + c] + xv.y * Wlin[(k + 1) * 16 + c] +
           xv.z * Wlin[(k + 2) * 16 + c] + xv.w * Wlin[(k + 3) * 16 + c];
  }
  XLh[node * 16 + c] = __float2bfloat16(al);
  XR[node * 16 + c] = ar;
  SK[node * 16 + c] = as_ + blin[c];
}

// XL2 (bf16) = H@Wl2 etc ; H:[N,16], W:[16,8]
__global__ void gemm3_16x8(const float* __restrict__ Hin,
                           const float* __restrict__ Wl, const float* __restrict__ Wr,
                           const float* __restrict__ Wlin, const float* __restrict__ blin,
                           __hip_bfloat16* __restrict__ XLh, float* __restrict__ XR,
                           float* __restrict__ SK, int N) {
  int gid = blockIdx.x * blockDim.x + threadIdx.x;
  int node = gid >> 3;
  int c = gid & 7;
  if (node >= N) return;
  const float* hrow = Hin + (size_t)node * 16;
  float al = 0.f, ar = 0.f, as_ = 0.f;
#pragma unroll
  for (int k = 0; k < 16; k++) {
    float hv = hrow[k];
    al += hv * Wl[k * 8 + c];
    ar += hv * Wr[k * 8 + c];
    as_ += hv * Wlin[k * 8 + c];
  }
  XLh[node * 8 + c] = __float2bfloat16(al);
  XR[node * 8 + c] = ar;
  SK[node * 8 + c] = as_ + blin[c];
}

// ---------------- GAT layer (pull mode over CSR, LDS edge cache) ----------------
// Pass 1: gather bf16 XL[src] (L2-resident), compute p=exp(score), cache raw v (bf16,
// per lane) and p (per edge) in an LDS pool; accumulate S0.
// Pass 2: entirely from LDS: alpha=p/S0, m=v*alpha, accumulate S1=sum exp(m t),
// S2=sum exp(m t)*m. Rare pool-overflow edges fall back to re-gather+recompute.
template <int C, int POOL>
__global__ __launch_bounds__(256) void gat_layer(
    const __hip_bfloat16* __restrict__ XLh, const float* __restrict__ XR,
    const float* __restrict__ SK, const float* __restrict__ att, const float* __restrict__ bias,
    const float* __restrict__ tp, const int* __restrict__ row_ptr, const int* __restrict__ ssrc,
    float* __restrict__ H, int N) {
  constexpr int NPB = 256 / C;
  __shared__ __hip_bfloat16 vpool[POOL * C];
  __shared__ float ppool[POOL];
  __shared__ int nbase[NPB + 1];
  int t = threadIdx.x;
  int g = t / C;
  int c = t % C;
  int node = blockIdx.x * NPB + g;
  bool valid = node < N;
  int beg = 0, end = 0;
  if (valid) {
    beg = row_ptr[node];
    end = row_ptr[node + 1];
  }
  int deg = end - beg;
  if (c == 0) nbase[g] = deg;
  __syncthreads();
  if (t == 0) {
    int run = 0;
#pragma unroll
    for (int i = 0; i < NPB; i++) {
      int d = nbase[i];
      nbase[i] = run;
      run += d;
    }
    nbase[NPB] = run;
  }
  __syncthreads();
  int base = nbase[g];

  float xr = valid ? XR[(size_t)node * C + c] : 0.f;
  float attc = att[c];
  float tval = tp[0];

  float S0 = 0.f;
  for (int jj = 0; jj < deg; ++jj) {
    int s = ssrc[beg + jj];
    __hip_bfloat16 raw = XLh[(size_t)s * C + c];
    float v = __bfloat162float(raw);
    float u = v + xr;
    float e = fmaxf(u, 0.2f * u) * attc;
#pragma unroll
    for (int m = 1; m < C; m <<= 1) e += __shfl_xor(e, m, C);
    float p = __expf(e);
    S0 += p;
    int slot = base + jj;
    if (slot < POOL) {
      vpool[slot * C + c] = raw;
      if (c == 0) ppool[slot] = p;
    }
  }
  // Groups only read their own slots (same wave) -> no barrier needed.
  float invS0 = (deg > 0) ? 1.0f / S0 : 0.f;
  float S1 = 0.f, S2 = 0.f;
  for (int jj = 0; jj < deg; ++jj) {
    int slot = base + jj;
    float v, p;
    if (slot < POOL) {
      v = __bfloat162float(vpool[slot * C + c]);
      p = ppool[slot];
    } else {  // rare overflow: recompute
      int s = ssrc[beg + jj];
      float vv = __bfloat162float(XLh[(size_t)s * C + c]);
      float u = vv + xr;
      float e = fmaxf(u, 0.2f * u) * attc;
#pragma unroll
      for (int m = 1; m < C; m <<= 1) e += __shfl_xor(e, m, C);
      v = vv;
      p = __expf(e);
    }
    float alpha = p * invS0;
    float mm = v * alpha;
    float w = __expf(mm * tval);
    S1 += w;
    S2 += w * mm;
  }
  if (valid) {
    float gat = (deg > 0) ? (S2 / S1) : 0.f;
    float h = gat + bias[c] + SK[(size_t)node * C + c];
    H[(size_t)node * C + c] = fmaxf(h, 0.f);
  }
}

// ---------------- MLP head ----------------
__global__ void head_kernel(const float* __restrict__ H2,
                            const float* __restrict__ W3, const float* __restrict__ b3,
                            const float* __restrict__ W4, const float* __restrict__ b4,
                            const float* __restrict__ W5, const float* __restrict__ b5,
                            const float* __restrict__ Wout, const float* __restrict__ bout,
                            float* __restrict__ out, int N) {
  int i = blockIdx.x * blockDim.x + threadIdx.x;
  if (i >= N) return;
  float h[8];
#pragma unroll
  for (int k = 0; k < 8; k++) h[k] = H2[(size_t)i * 8 + k];
  float s4 = 0.f;
#pragma unroll
  for (int cc = 0; cc < 8; cc++) {
    float z = b3[cc];
#pragma unroll
    for (int k = 0; k < 8; k++) z += h[k] * W3[k * 8 + cc];
    z = fmaxf(z, 0.f);
    s4 += z * W4[cc];
  }
  s4 = fmaxf(s4 + b4[0], 0.f);
  float s5 = fmaxf(s4 * W5[0] + b5[0], 0.f);
  float zo = s5 * Wout[0] + bout[0];
  float ls;
  if (zo >= 0.f)
    ls = -log1pf(expf(-zo));
  else
    ls = zo - log1pf(expf(zo));
  out[i] = ls;
}

extern "C" void kernel_launch(void* const* d_in, const int* in_sizes, int n_in,
                              void* d_out, int out_size, void* d_ws, size_t ws_size,
                              hipStream_t stream) {
  const float* x = (const float*)d_in[0];
  const int* ei = (const int*)d_in[1];
  const float* Wl1 = (const float*)d_in[3];
  const float* Wr1 = (const float*)d_in[4];
  const float* att1 = (const float*)d_in[5];
  const float* b1 = (const float*)d_in[6];
  const float* Wlin1 = (const float*)d_in[7];
  const float* blin1 = (const float*)d_in[8];
  const float* Wl2 = (const float*)d_in[9];
  const float* Wr2 = (const float*)d_in[10];
  const float* att2 = (const float*)d_in[11];
  const float* b2 = (const float*)d_in[12];
  const float* Wlin2 = (const float*)d_in[13];
  const float* blin2 = (const float*)d_in[14];
  const float* t = (const float*)d_in[15];
  const float* W3 = (const float*)d_in[16];
  const float* b3 = (const float*)d_in[17];
  const float* W4 = (const float*)d_in[18];
  const float* b4 = (const float*)d_in[19];
  const float* W5 = (const float*)d_in[20];
  const float* b5 = (const float*)d_in[21];
  const float* Wout = (const float*)d_in[22];
  const float* bout = (const float*)d_in[23];
  float* out = (float*)d_out;

  int N = in_sizes[0] / F_IN;
  int E = in_sizes[1] / 2;
  const int* src = ei;
  const int* dst = ei + E;
  int NB = (N + LOCAL - 1) >> LBITS;  // 391 for N=100000

  char* ws = (char*)d_ws;
  size_t off = 0;
  auto alloc = [&](size_t bytes) -> void* {
    void* p = ws + off;
    off = (off + bytes + 255) & ~(size_t)255;
    return p;
  };
  int* bcount = (int*)alloc((size_t)NB * 4);
  int* bbase = (int*)alloc((size_t)(NB + 1) * 4);
  int* bcursor = (int*)alloc((size_t)NB * 4);
  int* packed = (int*)alloc((size_t)E * 4);
  int* row_ptr = (int*)alloc((size_t)(N + 1) * 4);
  int* ssrc = (int*)alloc((size_t)E * 4);
  __hip_bfloat16* XL1 = (__hip_bfloat16*)alloc((size_t)N * C1 * 2);
  float* XR1 = (float*)alloc((size_t)N * C1 * 4);
  float* SK1 = (float*)alloc((size_t)N * C1 * 4);
  float* H1 = (float*)alloc((size_t)N * C1 * 4);
  __hip_bfloat16* XL2 = (__hip_bfloat16*)alloc((size_t)N * C2 * 2);
  float* XR2 = (float*)alloc((size_t)N * C2 * 4);
  float* SK2 = (float*)alloc((size_t)N * C2 * 4);
  float* H2 = (float*)alloc((size_t)N * C2 * 4);

  int nblkA = (E + 256 * ITEMS - 1) / (256 * ITEMS);

  hipLaunchKernelGGL(zero_int, dim3((NB + 255) / 256), dim3(256), 0, stream, bcount, NB);
  hipLaunchKernelGGL(bucket_hist, dim3(512), dim3(256), 0, stream, dst, bcount, E, NB);
  hipLaunchKernelGGL(bucket_scan, dim3(1), dim3(NB_MAX), 0, stream, bcount, bbase, bcursor, NB);
  hipLaunchKernelGGL(phaseA_lds, dim3(nblkA), dim3(256), 0, stream, src, dst, bcursor, packed, E,
                     NB);
  hipLaunchKernelGGL(phaseB_sort, dim3(NB), dim3(LOCAL), 0, stream, packed, bbase, row_ptr, ssrc, N,
                     E);
  hipLaunchKernelGGL(gemm3_128x16, dim3((N * 16 + 255) / 256), dim3(256), 0, stream, x, Wl1, Wr1,
                     Wlin1, blin1, XL1, XR1, SK1, N);
  hipLaunchKernelGGL((gat_layer<16, 768>), dim3((N + 15) / 16), dim3(256), 0, stream, XL1, XR1, SK1,
                     att1, b1, t, row_ptr, ssrc, H1, N);
  hipLaunchKernelGGL(gemm3_16x8, dim3((N * 8 + 255) / 256), dim3(256), 0, stream, H1, Wl2, Wr2,
                     Wlin2, blin2, XL2, XR2, SK2, N);
  hipLaunchKernelGGL((gat_layer<8, 1280>), dim3((N + 31) / 32), dim3(256), 0, stream, XL2, XR2, SK2,
                     att2, b2, t, row_ptr, ssrc, H2, N);
  hipLaunchKernelGGL(head_kernel, dim3((N + 255) / 256), dim3(256), 0, stream, H2, W3, b3, W4, b4,
                     W5, b5, Wout, bout, out, N);
}

// Round 5
// 520.227 us; speedup vs baseline: 2.4742x; 1.0899x over previous
//
#include <hip/hip_runtime.h>
#include <hip/hip_bf16.h>
#include <math.h>

#define F_IN 128
#define C1 16
#define C2 8

#define LBITS 8                 // 256 nodes per bucket
#define LOCAL (1 << LBITS)
#define NB_MAX 512              // supports N up to 131072
#define ITEMS 16                // edges per thread in phase A

// ---------------- utility ----------------
__global__ void zero_int(int* __restrict__ p, int n) {
  int i = blockIdx.x * blockDim.x + threadIdx.x;
  if (i < n) p[i] = 0;
}

// ---------------- two-level bucket sort by dst ----------------
__global__ void bucket_hist(const int* __restrict__ dst, int* __restrict__ bcount, int E, int NB) {
  __shared__ int h[NB_MAX];
  for (int i = threadIdx.x; i < NB; i += blockDim.x) h[i] = 0;
  __syncthreads();
  int stride = gridDim.x * blockDim.x;
  for (int e = blockIdx.x * blockDim.x + threadIdx.x; e < E; e += stride)
    atomicAdd(&h[dst[e] >> LBITS], 1);
  __syncthreads();
  for (int i = threadIdx.x; i < NB; i += blockDim.x)
    if (h[i]) atomicAdd(&bcount[i], h[i]);
}

__global__ void bucket_scan(const int* __restrict__ bcount, int* __restrict__ bbase,
                            int* __restrict__ bcursor, int NB) {
  __shared__ int sd[NB_MAX];
  int t = threadIdx.x;
  int v = (t < NB) ? bcount[t] : 0;
  sd[t] = v;
  __syncthreads();
  int acc = v;
  for (int off = 1; off < NB_MAX; off <<= 1) {
    int u = (t >= off) ? sd[t - off] : 0;
    __syncthreads();
    acc += u;
    sd[t] = acc;
    __syncthreads();
  }
  if (t < NB) {
    int excl = acc - v;
    bbase[t] = excl;
    bcursor[t] = excl;
    if (t == NB - 1) bbase[NB] = acc;
  }
}

__global__ void phaseA_lds(const int* __restrict__ src, const int* __restrict__ dst,
                           int* __restrict__ bcursor, int* __restrict__ packed, int E, int NB) {
  __shared__ int hist[NB_MAX];
  __shared__ int cur[NB_MAX];
  for (int i = threadIdx.x; i < NB; i += blockDim.x) hist[i] = 0;
  __syncthreads();
  int base = blockIdx.x * blockDim.x * ITEMS;
  int vals[ITEMS];
  int bkt[ITEMS];
#pragma unroll
  for (int k = 0; k < ITEMS; k++) {
    int e = base + k * blockDim.x + threadIdx.x;
    if (e < E) {
      int s = src[e];
      int d = dst[e];
      bkt[k] = d >> LBITS;
      vals[k] = (s << LBITS) | (d & (LOCAL - 1));
      atomicAdd(&hist[bkt[k]], 1);
    } else {
      bkt[k] = -1;
    }
  }
  __syncthreads();
  for (int i = threadIdx.x; i < NB; i += blockDim.x) {
    int c = hist[i];
    cur[i] = c ? atomicAdd(&bcursor[i], c) : 0;
  }
  __syncthreads();
#pragma unroll
  for (int k = 0; k < ITEMS; k++) {
    if (bkt[k] >= 0) {
      int p = atomicAdd(&cur[bkt[k]], 1);
      packed[p] = vals[k];
    }
  }
}

__global__ void phaseB_sort(const int* __restrict__ packed, const int* __restrict__ bbase,
                            int* __restrict__ row_ptr, int* __restrict__ ssrc, int N, int E) {
  __shared__ int h[LOCAL];
  __shared__ int sd[LOCAL];
  int b = blockIdx.x;
  int t = threadIdx.x;  // blockDim.x == LOCAL == 256
  int beg = bbase[b], end = bbase[b + 1];
  int node0 = b << LBITS;
  h[t] = 0;
  __syncthreads();
  for (int j = beg + t; j < end; j += blockDim.x) atomicAdd(&h[packed[j] & (LOCAL - 1)], 1);
  __syncthreads();
  int cnt = h[t];
  sd[t] = cnt;
  __syncthreads();
  int acc = cnt;
  for (int off = 1; off < LOCAL; off <<= 1) {
    int u = (t >= off) ? sd[t - off] : 0;
    __syncthreads();
    acc += u;
    sd[t] = acc;
    __syncthreads();
  }
  int myex = acc - cnt;
  int node = node0 + t;
  if (node < N) row_ptr[node] = beg + myex;
  h[t] = beg + myex;
  if (b == gridDim.x - 1 && t == 0) row_ptr[N] = E;
  __syncthreads();
  for (int j = beg + t; j < end; j += blockDim.x) {
    int v = packed[j];
    int p = atomicAdd(&h[v & (LOCAL - 1)], 1);
    ssrc[p] = v >> LBITS;
  }
}

// ---------------- dense transforms ----------------
__global__ void gemm3_128x16(const float* __restrict__ x,
                             const float* __restrict__ Wl, const float* __restrict__ Wr,
                             const float* __restrict__ Wlin, const float* __restrict__ blin,
                             __hip_bfloat16* __restrict__ XLh, float* __restrict__ XR,
                             float* __restrict__ SK, int N) {
  int gid = blockIdx.x * blockDim.x + threadIdx.x;
  int node = gid >> 4;
  int c = gid & 15;
  if (node >= N) return;
  const float4* xr4 = (const float4*)(x + (size_t)node * F_IN);
  float al = 0.f, ar = 0.f, as_ = 0.f;
#pragma unroll 8
  for (int kk = 0; kk < F_IN / 4; kk++) {
    float4 xv = xr4[kk];
    int k = kk * 4;
    al += xv.x * Wl[(k + 0) * 16 + c] + xv.y * Wl[(k + 1) * 16 + c] +
          xv.z * Wl[(k + 2) * 16 + c] + xv.w * Wl[(k + 3) * 16 + c];
    ar += xv.x * Wr[(k + 0) * 16 + c] + xv.y * Wr[(k + 1) * 16 + c] +
          xv.z * Wr[(k + 2) * 16 + c] + xv.w * Wr[(k + 3) * 16 + c];
    as_ += xv.x * Wlin[(k + 0) * 16 + c] + xv.y * Wlin[(k + 1) * 16 + c] +
           xv.z * Wlin[(k + 2) * 16 + c] + xv.w * Wlin[(k + 3) * 16 + c];
  }
  XLh[node * 16 + c] = __float2bfloat16(al);
  XR[node * 16 + c] = ar;
  SK[node * 16 + c] = as_ + blin[c];
}

__global__ void gemm3_16x8(const float* __restrict__ Hin,
                           const float* __restrict__ Wl, const float* __restrict__ Wr,
                           const float* __restrict__ Wlin, const float* __restrict__ blin,
                           __hip_bfloat16* __restrict__ XLh, float* __restrict__ XR,
                           float* __restrict__ SK, int N) {
  int gid = blockIdx.x * blockDim.x + threadIdx.x;
  int node = gid >> 3;
  int c = gid & 7;
  if (node >= N) return;
  const float* hrow = Hin + (size_t)node * 16;
  float al = 0.f, ar = 0.f, as_ = 0.f;
#pragma unroll
  for (int k = 0; k < 16; k++) {
    float hv = hrow[k];
    al += hv * Wl[k * 8 + c];
    ar += hv * Wr[k * 8 + c];
    as_ += hv * Wlin[k * 8 + c];
  }
  XLh[node * 8 + c] = __float2bfloat16(al);
  XR[node * 8 + c] = ar;
  SK[node * 8 + c] = as_ + blin[c];
}

// ---------------- GAT layer: decoupled gather + LDS-resident compute ----------------
// A block owns NPB=256/C consecutive nodes; their CSR edges are CONTIGUOUS
// [bbeg, bend). Phase G: all 256 threads stream-gather XL[src] for every edge
// slot into vpool (independent loads -> deep MLP; coalesced LDS writes).
// Phase 1: per-group (C lanes/node) score+softmax-denominator from LDS only.
// Phase 2: aggregation softmax from LDS only. Overflow slots (>=POOL, ~never)
// fall back to global recompute for correctness.
template <int C, int POOL>
__global__ __launch_bounds__(256) void gat_layer(
    const __hip_bfloat16* __restrict__ XLh, const float* __restrict__ XR,
    const float* __restrict__ SK, const float* __restrict__ att, const float* __restrict__ bias,
    const float* __restrict__ tp, const int* __restrict__ row_ptr, const int* __restrict__ ssrc,
    float* __restrict__ H, int N) {
  constexpr int NPB = 256 / C;
  __shared__ __align__(4) unsigned short vpool[POOL * C];
  __shared__ float ppool[POOL];
  int t = threadIdx.x;
  int node0 = blockIdx.x * NPB;
  int tailN = (node0 + NPB < N) ? (node0 + NPB) : N;
  int bbeg = row_ptr[node0];   // same address for all threads -> broadcast
  int bend = row_ptr[tailN];
  int nE = bend - bbeg;
  int nCap = (nE < POOL) ? nE : POOL;

  // ---- Phase G: cooperative gather (ushort2 = 2 channels per thread) ----
  {
    constexpr int PAIRS = C / 2;
    constexpr int SPI = 256 / PAIRS;  // slots per iteration
    int slot = t / PAIRS;
    int cp = t % PAIRS;
    const unsigned short* XLu = (const unsigned short*)XLh;
    for (int s0 = slot; s0 < nCap; s0 += SPI) {
      int s = ssrc[bbeg + s0];  // PAIRS lanes same address -> broadcast
      ushort2 val = *(const ushort2*)(XLu + (size_t)s * C + cp * 2);
      *(ushort2*)&vpool[s0 * C + cp * 2] = val;
    }
  }
  __syncthreads();

  int g = t / C;
  int c = t % C;
  int node = node0 + g;
  bool valid = node < N;
  int beg = 0, end = 0;
  if (valid) {
    beg = row_ptr[node];
    end = row_ptr[node + 1];
  }
  int deg = end - beg;
  int base = beg - bbeg;

  float xr = valid ? XR[(size_t)node * C + c] : 0.f;
  float attc = att[c];
  float tval = tp[0];

  // ---- Phase 1: scores from LDS ----
  float S0 = 0.f;
  for (int jj = 0; jj < deg; ++jj) {
    int slot = base + jj;
    float v;
    if (slot < POOL) {
      v = __uint_as_float(((unsigned)vpool[slot * C + c]) << 16);
    } else {  // rare overflow
      int s = ssrc[beg + jj];
      v = __bfloat162float(XLh[(size_t)s * C + c]);
    }
    float u = v + xr;
    float e = fmaxf(u, 0.2f * u) * attc;
#pragma unroll
    for (int m = 1; m < C; m <<= 1) e += __shfl_xor(e, m, C);
    float p = __expf(e);
    S0 += p;
    if (slot < POOL && c == 0) ppool[slot] = p;
  }
  float invS0 = (deg > 0) ? 1.0f / S0 : 0.f;

  // ---- Phase 2: aggregation softmax from LDS ----
  float S1 = 0.f, S2 = 0.f;
  for (int jj = 0; jj < deg; ++jj) {
    int slot = base + jj;
    float v, p;
    if (slot < POOL) {
      v = __uint_as_float(((unsigned)vpool[slot * C + c]) << 16);
      p = ppool[slot];
    } else {  // rare overflow: recompute
      int s = ssrc[beg + jj];
      v = __bfloat162float(XLh[(size_t)s * C + c]);
      float u = v + xr;
      float e = fmaxf(u, 0.2f * u) * attc;
#pragma unroll
      for (int m = 1; m < C; m <<= 1) e += __shfl_xor(e, m, C);
      p = __expf(e);
    }
    float alpha = p * invS0;
    float mm = v * alpha;
    float w = __expf(mm * tval);
    S1 += w;
    S2 += w * mm;
  }
  if (valid) {
    float gat = (deg > 0) ? (S2 / S1) : 0.f;
    float h = gat + bias[c] + SK[(size_t)node * C + c];
    H[(size_t)node * C + c] = fmaxf(h, 0.f);
  }
}

// ---------------- MLP head ----------------
__global__ void head_kernel(const float* __restrict__ H2,
                            const float* __restrict__ W3, const float* __restrict__ b3,
                            const float* __restrict__ W4, const float* __restrict__ b4,
                            const float* __restrict__ W5, const float* __restrict__ b5,
                            const float* __restrict__ Wout, const float* __restrict__ bout,
                            float* __restrict__ out, int N) {
  int i = blockIdx.x * blockDim.x + threadIdx.x;
  if (i >= N) return;
  float h[8];
#pragma unroll
  for (int k = 0; k < 8; k++) h[k] = H2[(size_t)i * 8 + k];
  float s4 = 0.f;
#pragma unroll
  for (int cc = 0; cc < 8; cc++) {
    float z = b3[cc];
#pragma unroll
    for (int k = 0; k < 8; k++) z += h[k] * W3[k * 8 + cc];
    z = fmaxf(z, 0.f);
    s4 += z * W4[cc];
  }
  s4 = fmaxf(s4 + b4[0], 0.f);
  float s5 = fmaxf(s4 * W5[0] + b5[0], 0.f);
  float zo = s5 * Wout[0] + bout[0];
  float ls;
  if (zo >= 0.f)
    ls = -log1pf(expf(-zo));
  else
    ls = zo - log1pf(expf(zo));
  out[i] = ls;
}

extern "C" void kernel_launch(void* const* d_in, const int* in_sizes, int n_in,
                              void* d_out, int out_size, void* d_ws, size_t ws_size,
                              hipStream_t stream) {
  const float* x = (const float*)d_in[0];
  const int* ei = (const int*)d_in[1];
  const float* Wl1 = (const float*)d_in[3];
  const float* Wr1 = (const float*)d_in[4];
  const float* att1 = (const float*)d_in[5];
  const float* b1 = (const float*)d_in[6];
  const float* Wlin1 = (const float*)d_in[7];
  const float* blin1 = (const float*)d_in[8];
  const float* Wl2 = (const float*)d_in[9];
  const float* Wr2 = (const float*)d_in[10];
  const float* att2 = (const float*)d_in[11];
  const float* b2 = (const float*)d_in[12];
  const float* Wlin2 = (const float*)d_in[13];
  const float* blin2 = (const float*)d_in[14];
  const float* t = (const float*)d_in[15];
  const float* W3 = (const float*)d_in[16];
  const float* b3 = (const float*)d_in[17];
  const float* W4 = (const float*)d_in[18];
  const float* b4 = (const float*)d_in[19];
  const float* W5 = (const float*)d_in[20];
  const float* b5 = (const float*)d_in[21];
  const float* Wout = (const float*)d_in[22];
  const float* bout = (const float*)d_in[23];
  float* out = (float*)d_out;

  int N = in_sizes[0] / F_IN;
  int E = in_sizes[1] / 2;
  const int* src = ei;
  const int* dst = ei + E;
  int NB = (N + LOCAL - 1) >> LBITS;  // 391 for N=100000

  char* ws = (char*)d_ws;
  size_t off = 0;
  auto alloc = [&](size_t bytes) -> void* {
    void* p = ws + off;
    off = (off + bytes + 255) & ~(size_t)255;
    return p;
  };
  int* bcount = (int*)alloc((size_t)NB * 4);
  int* bbase = (int*)alloc((size_t)(NB + 1) * 4);
  int* bcursor = (int*)alloc((size_t)NB * 4);
  int* packed = (int*)alloc((size_t)E * 4);
  int* row_ptr = (int*)alloc((size_t)(N + 1) * 4);
  int* ssrc = (int*)alloc((size_t)E * 4);
  __hip_bfloat16* XL1 = (__hip_bfloat16*)alloc((size_t)N * C1 * 2);
  float* XR1 = (float*)alloc((size_t)N * C1 * 4);
  float* SK1 = (float*)alloc((size_t)N * C1 * 4);
  float* H1 = (float*)alloc((size_t)N * C1 * 4);
  __hip_bfloat16* XL2 = (__hip_bfloat16*)alloc((size_t)N * C2 * 2);
  float* XR2 = (float*)alloc((size_t)N * C2 * 4);
  float* SK2 = (float*)alloc((size_t)N * C2 * 4);
  float* H2 = (float*)alloc((size_t)N * C2 * 4);

  int nblkA = (E + 256 * ITEMS - 1) / (256 * ITEMS);

  hipLaunchKernelGGL(zero_int, dim3((NB + 255) / 256), dim3(256), 0, stream, bcount, NB);
  hipLaunchKernelGGL(bucket_hist, dim3(512), dim3(256), 0, stream, dst, bcount, E, NB);
  hipLaunchKernelGGL(bucket_scan, dim3(1), dim3(NB_MAX), 0, stream, bcount, bbase, bcursor, NB);
  hipLaunchKernelGGL(phaseA_lds, dim3(nblkA), dim3(256), 0, stream, src, dst, bcursor, packed, E,
                     NB);
  hipLaunchKernelGGL(phaseB_sort, dim3(NB), dim3(LOCAL), 0, stream, packed, bbase, row_ptr, ssrc, N,
                     E);
  hipLaunchKernelGGL(gemm3_128x16, dim3((N * 16 + 255) / 256), dim3(256), 0, stream, x, Wl1, Wr1,
                     Wlin1, blin1, XL1, XR1, SK1, N);
  hipLaunchKernelGGL((gat_layer<16, 640>), dim3((N + 15) / 16), dim3(256), 0, stream, XL1, XR1, SK1,
                     att1, b1, t, row_ptr, ssrc, H1, N);
  hipLaunchKernelGGL(gemm3_16x8, dim3((N * 8 + 255) / 256), dim3(256), 0, stream, H1, Wl2, Wr2,
                     Wlin2, blin2, XL2, XR2, SK2, N);
  hipLaunchKernelGGL((gat_layer<8, 1280>), dim3((N + 31) / 32), dim3(256), 0, stream, XL2, XR2, SK2,
                     att2, b2, t, row_ptr, ssrc, H2, N);
  hipLaunchKernelGGL(head_kernel, dim3((N + 255) / 256), dim3(256), 0, stream, H2, W3, b3, W4, b4,
                     W5, b5, Wout, bout, out, N);
}

// Round 6
// 468.612 us; speedup vs baseline: 2.7467x; 1.1101x over previous
//
#include <hip/hip_runtime.h>
#include <hip/hip_bf16.h>
#include <math.h>

#define F_IN 128
#define C1 16
#define C2 8

#define LBITS 8                 // 256 nodes per bucket
#define LOCAL (1 << LBITS)
#define NB_MAX 512              // supports N up to 131072
#define ITEMS 16                // edges per thread in phase A

static __device__ __forceinline__ unsigned short f2bf(float f) {
  __hip_bfloat16 h = __float2bfloat16(f);
  return *(unsigned short*)&h;
}

// ---------------- utility ----------------
__global__ void zero_int(int* __restrict__ p, int n) {
  int i = blockIdx.x * blockDim.x + threadIdx.x;
  if (i < n) p[i] = 0;
}

// ---------------- two-level bucket sort by dst ----------------
__global__ void bucket_hist(const int* __restrict__ dst, int* __restrict__ bcount, int E, int NB) {
  __shared__ int h[NB_MAX];
  for (int i = threadIdx.x; i < NB; i += blockDim.x) h[i] = 0;
  __syncthreads();
  int stride = gridDim.x * blockDim.x;
  for (int e = blockIdx.x * blockDim.x + threadIdx.x; e < E; e += stride)
    atomicAdd(&h[dst[e] >> LBITS], 1);
  __syncthreads();
  for (int i = threadIdx.x; i < NB; i += blockDim.x)
    if (h[i]) atomicAdd(&bcount[i], h[i]);
}

__global__ void bucket_scan(const int* __restrict__ bcount, int* __restrict__ bbase,
                            int* __restrict__ bcursor, int NB) {
  __shared__ int sd[NB_MAX];
  int t = threadIdx.x;
  int v = (t < NB) ? bcount[t] : 0;
  sd[t] = v;
  __syncthreads();
  int acc = v;
  for (int off = 1; off < NB_MAX; off <<= 1) {
    int u = (t >= off) ? sd[t - off] : 0;
    __syncthreads();
    acc += u;
    sd[t] = acc;
    __syncthreads();
  }
  if (t < NB) {
    int excl = acc - v;
    bbase[t] = excl;
    bcursor[t] = excl;
    if (t == NB - 1) bbase[NB] = acc;
  }
}

__global__ void phaseA_lds(const int* __restrict__ src, const int* __restrict__ dst,
                           int* __restrict__ bcursor, int* __restrict__ packed, int E, int NB) {
  __shared__ int hist[NB_MAX];
  __shared__ int cur[NB_MAX];
  for (int i = threadIdx.x; i < NB; i += blockDim.x) hist[i] = 0;
  __syncthreads();
  int base = blockIdx.x * blockDim.x * ITEMS;
  int vals[ITEMS];
  int bkt[ITEMS];
#pragma unroll
  for (int k = 0; k < ITEMS; k++) {
    int e = base + k * blockDim.x + threadIdx.x;
    if (e < E) {
      int s = src[e];
      int d = dst[e];
      bkt[k] = d >> LBITS;
      vals[k] = (s << LBITS) | (d & (LOCAL - 1));
      atomicAdd(&hist[bkt[k]], 1);
    } else {
      bkt[k] = -1;
    }
  }
  __syncthreads();
  for (int i = threadIdx.x; i < NB; i += blockDim.x) {
    int c = hist[i];
    cur[i] = c ? atomicAdd(&bcursor[i], c) : 0;
  }
  __syncthreads();
#pragma unroll
  for (int k = 0; k < ITEMS; k++) {
    if (bkt[k] >= 0) {
      int p = atomicAdd(&cur[bkt[k]], 1);
      packed[p] = vals[k];
    }
  }
}

__global__ void phaseB_sort(const int* __restrict__ packed, const int* __restrict__ bbase,
                            int* __restrict__ row_ptr, int* __restrict__ ssrc, int N, int E) {
  __shared__ int h[LOCAL];
  __shared__ int sd[LOCAL];
  int b = blockIdx.x;
  int t = threadIdx.x;  // blockDim.x == LOCAL == 256
  int beg = bbase[b], end = bbase[b + 1];
  int node0 = b << LBITS;
  h[t] = 0;
  __syncthreads();
  for (int j = beg + t; j < end; j += blockDim.x) atomicAdd(&h[packed[j] & (LOCAL - 1)], 1);
  __syncthreads();
  int cnt = h[t];
  sd[t] = cnt;
  __syncthreads();
  int acc = cnt;
  for (int off = 1; off < LOCAL; off <<= 1) {
    int u = (t >= off) ? sd[t - off] : 0;
    __syncthreads();
    acc += u;
    sd[t] = acc;
    __syncthreads();
  }
  int myex = acc - cnt;
  int node = node0 + t;
  if (node < N) row_ptr[node] = beg + myex;
  h[t] = beg + myex;
  if (b == gridDim.x - 1 && t == 0) row_ptr[N] = E;
  __syncthreads();
  for (int j = beg + t; j < end; j += blockDim.x) {
    int v = packed[j];
    int p = atomicAdd(&h[v & (LOCAL - 1)], 1);
    ssrc[p] = v >> LBITS;
  }
}

// ---------------- dense transforms (thread-per-node, scalar weight loads) ----------------
// Thread i owns node i: 48 accumulators; weight indices are wave-uniform ->
// compiler emits s_load (SGPR broadcast); inner loop is pure v_fma.
__global__ __launch_bounds__(256) void gemm3_128x16(
    const float* __restrict__ x, const float* __restrict__ Wl, const float* __restrict__ Wr,
    const float* __restrict__ Wlin, const float* __restrict__ blin,
    __hip_bfloat16* __restrict__ XLh, float* __restrict__ XR, float* __restrict__ SK, int N) {
  int node = blockIdx.x * blockDim.x + threadIdx.x;
  if (node >= N) return;
  const float4* xr4 = (const float4*)(x + (size_t)node * F_IN);
  float al[16], ar[16], as_[16];
#pragma unroll
  for (int c = 0; c < 16; c++) {
    al[c] = 0.f;
    ar[c] = 0.f;
    as_[c] = 0.f;
  }
  for (int kk = 0; kk < F_IN / 4; kk++) {
    float4 xv = xr4[kk];
    float xs[4] = {xv.x, xv.y, xv.z, xv.w};
#pragma unroll
    for (int j = 0; j < 4; j++) {
      int k = kk * 4 + j;
#pragma unroll
      for (int c = 0; c < 16; c++) {
        al[c] = fmaf(xs[j], Wl[k * 16 + c], al[c]);
        ar[c] = fmaf(xs[j], Wr[k * 16 + c], ar[c]);
        as_[c] = fmaf(xs[j], Wlin[k * 16 + c], as_[c]);
      }
    }
  }
  // XL: pack 16 bf16 -> 2x uint4 stores
  unsigned int pk[8];
#pragma unroll
  for (int i = 0; i < 8; i++)
    pk[i] = (unsigned)f2bf(al[2 * i]) | ((unsigned)f2bf(al[2 * i + 1]) << 16);
  uint4* xlp = (uint4*)(XLh + (size_t)node * 16);
  xlp[0] = make_uint4(pk[0], pk[1], pk[2], pk[3]);
  xlp[1] = make_uint4(pk[4], pk[5], pk[6], pk[7]);
  float4* xrp = (float4*)(XR + (size_t)node * 16);
  float4* skp = (float4*)(SK + (size_t)node * 16);
#pragma unroll
  for (int q = 0; q < 4; q++) {
    xrp[q] = make_float4(ar[4 * q], ar[4 * q + 1], ar[4 * q + 2], ar[4 * q + 3]);
    skp[q] = make_float4(as_[4 * q] + blin[4 * q], as_[4 * q + 1] + blin[4 * q + 1],
                         as_[4 * q + 2] + blin[4 * q + 2], as_[4 * q + 3] + blin[4 * q + 3]);
  }
}

__global__ __launch_bounds__(256) void gemm3_16x8(
    const float* __restrict__ Hin, const float* __restrict__ Wl, const float* __restrict__ Wr,
    const float* __restrict__ Wlin, const float* __restrict__ blin,
    __hip_bfloat16* __restrict__ XLh, float* __restrict__ XR, float* __restrict__ SK, int N) {
  int node = blockIdx.x * blockDim.x + threadIdx.x;
  if (node >= N) return;
  const float4* hr4 = (const float4*)(Hin + (size_t)node * 16);
  float al[8], ar[8], as_[8];
#pragma unroll
  for (int c = 0; c < 8; c++) {
    al[c] = 0.f;
    ar[c] = 0.f;
    as_[c] = 0.f;
  }
#pragma unroll
  for (int kk = 0; kk < 4; kk++) {
    float4 hv = hr4[kk];
    float hs[4] = {hv.x, hv.y, hv.z, hv.w};
#pragma unroll
    for (int j = 0; j < 4; j++) {
      int k = kk * 4 + j;
#pragma unroll
      for (int c = 0; c < 8; c++) {
        al[c] = fmaf(hs[j], Wl[k * 8 + c], al[c]);
        ar[c] = fmaf(hs[j], Wr[k * 8 + c], ar[c]);
        as_[c] = fmaf(hs[j], Wlin[k * 8 + c], as_[c]);
      }
    }
  }
  unsigned int pk[4];
#pragma unroll
  for (int i = 0; i < 4; i++)
    pk[i] = (unsigned)f2bf(al[2 * i]) | ((unsigned)f2bf(al[2 * i + 1]) << 16);
  *(uint4*)(XLh + (size_t)node * 8) = make_uint4(pk[0], pk[1], pk[2], pk[3]);
  float4* xrp = (float4*)(XR + (size_t)node * 8);
  float4* skp = (float4*)(SK + (size_t)node * 8);
#pragma unroll
  for (int q = 0; q < 2; q++) {
    xrp[q] = make_float4(ar[4 * q], ar[4 * q + 1], ar[4 * q + 2], ar[4 * q + 3]);
    skp[q] = make_float4(as_[4 * q] + blin[4 * q], as_[4 * q + 1] + blin[4 * q + 1],
                         as_[4 * q + 2] + blin[4 * q + 2], as_[4 * q + 3] + blin[4 * q + 3]);
  }
}

// ---------------- GAT layer: decoupled gather + LDS-resident compute ----------------
template <int C, int POOL>
__global__ __launch_bounds__(256) void gat_layer(
    const __hip_bfloat16* __restrict__ XLh, const float* __restrict__ XR,
    const float* __restrict__ SK, const float* __restrict__ att, const float* __restrict__ bias,
    const float* __restrict__ tp, const int* __restrict__ row_ptr, const int* __restrict__ ssrc,
    float* __restrict__ H, int N) {
  constexpr int NPB = 256 / C;
  __shared__ __align__(4) unsigned short vpool[POOL * C];
  __shared__ float ppool[POOL];
  int t = threadIdx.x;
  int node0 = blockIdx.x * NPB;
  int tailN = (node0 + NPB < N) ? (node0 + NPB) : N;
  int bbeg = row_ptr[node0];
  int bend = row_ptr[tailN];
  int nE = bend - bbeg;
  int nCap = (nE < POOL) ? nE : POOL;

  // ---- Phase G: cooperative gather (ushort2 = 2 channels per thread) ----
  {
    constexpr int PAIRS = C / 2;
    constexpr int SPI = 256 / PAIRS;
    int slot = t / PAIRS;
    int cp = t % PAIRS;
    const unsigned short* XLu = (const unsigned short*)XLh;
    for (int s0 = slot; s0 < nCap; s0 += SPI) {
      int s = ssrc[bbeg + s0];
      ushort2 val = *(const ushort2*)(XLu + (size_t)s * C + cp * 2);
      *(ushort2*)&vpool[s0 * C + cp * 2] = val;
    }
  }
  __syncthreads();

  int g = t / C;
  int c = t % C;
  int node = node0 + g;
  bool valid = node < N;
  int beg = 0, end = 0;
  if (valid) {
    beg = row_ptr[node];
    end = row_ptr[node + 1];
  }
  int deg = end - beg;
  int base = beg - bbeg;

  float xr = valid ? XR[(size_t)node * C + c] : 0.f;
  float attc = att[c];
  float tval = tp[0];

  float S0 = 0.f;
  for (int jj = 0; jj < deg; ++jj) {
    int slot = base + jj;
    float v;
    if (slot < POOL) {
      v = __uint_as_float(((unsigned)vpool[slot * C + c]) << 16);
    } else {
      int s = ssrc[beg + jj];
      v = __bfloat162float(XLh[(size_t)s * C + c]);
    }
    float u = v + xr;
    float e = fmaxf(u, 0.2f * u) * attc;
#pragma unroll
    for (int m = 1; m < C; m <<= 1) e += __shfl_xor(e, m, C);
    float p = __expf(e);
    S0 += p;
    if (slot < POOL && c == 0) ppool[slot] = p;
  }
  float invS0 = (deg > 0) ? 1.0f / S0 : 0.f;

  float S1 = 0.f, S2 = 0.f;
  for (int jj = 0; jj < deg; ++jj) {
    int slot = base + jj;
    float v, p;
    if (slot < POOL) {
      v = __uint_as_float(((unsigned)vpool[slot * C + c]) << 16);
      p = ppool[slot];
    } else {
      int s = ssrc[beg + jj];
      v = __bfloat162float(XLh[(size_t)s * C + c]);
      float u = v + xr;
      float e = fmaxf(u, 0.2f * u) * attc;
#pragma unroll
      for (int m = 1; m < C; m <<= 1) e += __shfl_xor(e, m, C);
      p = __expf(e);
    }
    float alpha = p * invS0;
    float mm = v * alpha;
    float w = __expf(mm * tval);
    S1 += w;
    S2 += w * mm;
  }
  if (valid) {
    float gat = (deg > 0) ? (S2 / S1) : 0.f;
    float h = gat + bias[c] + SK[(size_t)node * C + c];
    H[(size_t)node * C + c] = fmaxf(h, 0.f);
  }
}

// ---------------- MLP head ----------------
__global__ void head_kernel(const float* __restrict__ H2,
                            const float* __restrict__ W3, const float* __restrict__ b3,
                            const float* __restrict__ W4, const float* __restrict__ b4,
                            const float* __restrict__ W5, const float* __restrict__ b5,
                            const float* __restrict__ Wout, const float* __restrict__ bout,
                            float* __restrict__ out, int N) {
  int i = blockIdx.x * blockDim.x + threadIdx.x;
  if (i >= N) return;
  const float4* h4 = (const float4*)(H2 + (size_t)i * 8);
  float4 ha = h4[0], hb = h4[1];
  float h[8] = {ha.x, ha.y, ha.z, ha.w, hb.x, hb.y, hb.z, hb.w};
  float s4 = 0.f;
#pragma unroll
  for (int cc = 0; cc < 8; cc++) {
    float z = b3[cc];
#pragma unroll
    for (int k = 0; k < 8; k++) z = fmaf(h[k], W3[k * 8 + cc], z);
    z = fmaxf(z, 0.f);
    s4 = fmaf(z, W4[cc], s4);
  }
  s4 = fmaxf(s4 + b4[0], 0.f);
  float s5 = fmaxf(fmaf(s4, W5[0], b5[0]), 0.f);
  float zo = fmaf(s5, Wout[0], bout[0]);
  float ls;
  if (zo >= 0.f)
    ls = -log1pf(expf(-zo));
  else
    ls = zo - log1pf(expf(zo));
  out[i] = ls;
}

extern "C" void kernel_launch(void* const* d_in, const int* in_sizes, int n_in,
                              void* d_out, int out_size, void* d_ws, size_t ws_size,
                              hipStream_t stream) {
  const float* x = (const float*)d_in[0];
  const int* ei = (const int*)d_in[1];
  const float* Wl1 = (const float*)d_in[3];
  const float* Wr1 = (const float*)d_in[4];
  const float* att1 = (const float*)d_in[5];
  const float* b1 = (const float*)d_in[6];
  const float* Wlin1 = (const float*)d_in[7];
  const float* blin1 = (const float*)d_in[8];
  const float* Wl2 = (const float*)d_in[9];
  const float* Wr2 = (const float*)d_in[10];
  const float* att2 = (const float*)d_in[11];
  const float* b2 = (const float*)d_in[12];
  const float* Wlin2 = (const float*)d_in[13];
  const float* blin2 = (const float*)d_in[14];
  const float* t = (const float*)d_in[15];
  const float* W3 = (const float*)d_in[16];
  const float* b3 = (const float*)d_in[17];
  const float* W4 = (const float*)d_in[18];
  const float* b4 = (const float*)d_in[19];
  const float* W5 = (const float*)d_in[20];
  const float* b5 = (const float*)d_in[21];
  const float* Wout = (const float*)d_in[22];
  const float* bout = (const float*)d_in[23];
  float* out = (float*)d_out;

  int N = in_sizes[0] / F_IN;
  int E = in_sizes[1] / 2;
  const int* src = ei;
  const int* dst = ei + E;
  int NB = (N + LOCAL - 1) >> LBITS;  // 391 for N=100000

  char* ws = (char*)d_ws;
  size_t off = 0;
  auto alloc = [&](size_t bytes) -> void* {
    void* p = ws + off;
    off = (off + bytes + 255) & ~(size_t)255;
    return p;
  };
  int* bcount = (int*)alloc((size_t)NB * 4);
  int* bbase = (int*)alloc((size_t)(NB + 1) * 4);
  int* bcursor = (int*)alloc((size_t)NB * 4);
  int* packed = (int*)alloc((size_t)E * 4);
  int* row_ptr = (int*)alloc((size_t)(N + 1) * 4);
  int* ssrc = (int*)alloc((size_t)E * 4);
  __hip_bfloat16* XL1 = (__hip_bfloat16*)alloc((size_t)N * C1 * 2);
  float* XR1 = (float*)alloc((size_t)N * C1 * 4);
  float* SK1 = (float*)alloc((size_t)N * C1 * 4);
  float* H1 = (float*)alloc((size_t)N * C1 * 4);
  __hip_bfloat16* XL2 = (__hip_bfloat16*)alloc((size_t)N * C2 * 2);
  float* XR2 = (float*)alloc((size_t)N * C2 * 4);
  float* SK2 = (float*)alloc((size_t)N * C2 * 4);
  float* H2 = (float*)alloc((size_t)N * C2 * 4);

  int nblkA = (E + 256 * ITEMS - 1) / (256 * ITEMS);

  hipLaunchKernelGGL(zero_int, dim3((NB + 255) / 256), dim3(256), 0, stream, bcount, NB);
  hipLaunchKernelGGL(bucket_hist, dim3(512), dim3(256), 0, stream, dst, bcount, E, NB);
  hipLaunchKernelGGL(bucket_scan, dim3(1), dim3(NB_MAX), 0, stream, bcount, bbase, bcursor, NB);
  hipLaunchKernelGGL(phaseA_lds, dim3(nblkA), dim3(256), 0, stream, src, dst, bcursor, packed, E,
                     NB);
  hipLaunchKernelGGL(phaseB_sort, dim3(NB), dim3(LOCAL), 0, stream, packed, bbase, row_ptr, ssrc, N,
                     E);
  hipLaunchKernelGGL(gemm3_128x16, dim3((N + 255) / 256), dim3(256), 0, stream, x, Wl1, Wr1,
                     Wlin1, blin1, XL1, XR1, SK1, N);
  hipLaunchKernelGGL((gat_layer<16, 640>), dim3((N + 15) / 16), dim3(256), 0, stream, XL1, XR1, SK1,
                     att1, b1, t, row_ptr, ssrc, H1, N);
  hipLaunchKernelGGL(gemm3_16x8, dim3((N + 255) / 256), dim3(256), 0, stream, H1, Wl2, Wr2,
                     Wlin2, blin2, XL2, XR2, SK2, N);
  hipLaunchKernelGGL((gat_layer<8, 1280>), dim3((N + 31) / 32), dim3(256), 0, stream, XL2, XR2, SK2,
                     att2, b2, t, row_ptr, ssrc, H2, N);
  hipLaunchKernelGGL(head_kernel, dim3((N + 255) / 256), dim3(256), 0, stream, H2, W3, b3, W4, b4,
                     W5, b5, Wout, bout, out, N);
}

// Round 7
// 355.745 us; speedup vs baseline: 3.6182x; 1.3173x over previous
//
#include <hip/hip_runtime.h>
#include <hip/hip_bf16.h>
#include <math.h>

#define F_IN 128
#define C1 16
#define C2 8

#define LBITS 8                 // 256 nodes per bucket
#define LOCAL (1 << LBITS)
#define NB_MAX 512              // supports N up to 131072
#define ITEMS 16                // edges per thread in phase A

static __device__ __forceinline__ unsigned short f2bf(float f) {
  __hip_bfloat16 h = __float2bfloat16(f);
  return *(unsigned short*)&h;
}

// ---------------- two-level bucket sort by dst ----------------
__global__ void bucket_hist(const int* __restrict__ dst, int* __restrict__ bcount, int E, int NB) {
  __shared__ int h[NB_MAX];
  for (int i = threadIdx.x; i < NB; i += blockDim.x) h[i] = 0;
  __syncthreads();
  int stride = gridDim.x * blockDim.x;
  for (int e = blockIdx.x * blockDim.x + threadIdx.x; e < E; e += stride)
    atomicAdd(&h[dst[e] >> LBITS], 1);
  __syncthreads();
  for (int i = threadIdx.x; i < NB; i += blockDim.x)
    if (h[i]) atomicAdd(&bcount[i], h[i]);
}

__global__ void bucket_scan(const int* __restrict__ bcount, int* __restrict__ bbase,
                            int* __restrict__ bcursor, int NB) {
  __shared__ int sd[NB_MAX];
  int t = threadIdx.x;
  int v = (t < NB) ? bcount[t] : 0;
  sd[t] = v;
  __syncthreads();
  int acc = v;
  for (int off = 1; off < NB_MAX; off <<= 1) {
    int u = (t >= off) ? sd[t - off] : 0;
    __syncthreads();
    acc += u;
    sd[t] = acc;
    __syncthreads();
  }
  if (t < NB) {
    int excl = acc - v;
    bbase[t] = excl;
    bcursor[t] = excl;
    if (t == NB - 1) bbase[NB] = acc;
  }
}

__global__ void phaseA_lds(const int* __restrict__ src, const int* __restrict__ dst,
                           int* __restrict__ bcursor, int* __restrict__ packed, int E, int NB) {
  __shared__ int hist[NB_MAX];
  __shared__ int cur[NB_MAX];
  for (int i = threadIdx.x; i < NB; i += blockDim.x) hist[i] = 0;
  __syncthreads();
  int base = blockIdx.x * blockDim.x * ITEMS;
  int vals[ITEMS];
  int bkt[ITEMS];
#pragma unroll
  for (int k = 0; k < ITEMS; k++) {
    int e = base + k * blockDim.x + threadIdx.x;
    if (e < E) {
      int s = src[e];
      int d = dst[e];
      bkt[k] = d >> LBITS;
      vals[k] = (s << LBITS) | (d & (LOCAL - 1));
      atomicAdd(&hist[bkt[k]], 1);
    } else {
      bkt[k] = -1;
    }
  }
  __syncthreads();
  for (int i = threadIdx.x; i < NB; i += blockDim.x) {
    int c = hist[i];
    cur[i] = c ? atomicAdd(&bcursor[i], c) : 0;
  }
  __syncthreads();
#pragma unroll
  for (int k = 0; k < ITEMS; k++) {
    if (bkt[k] >= 0) {
      int p = atomicAdd(&cur[bkt[k]], 1);
      packed[p] = vals[k];
    }
  }
}

__global__ void phaseB_sort(const int* __restrict__ packed, const int* __restrict__ bbase,
                            int* __restrict__ row_ptr, int* __restrict__ ssrc, int N, int E) {
  __shared__ int h[LOCAL];
  __shared__ int sd[LOCAL];
  int b = blockIdx.x;
  int t = threadIdx.x;  // blockDim.x == LOCAL == 256
  int beg = bbase[b], end = bbase[b + 1];
  int node0 = b << LBITS;
  h[t] = 0;
  __syncthreads();
  for (int j = beg + t; j < end; j += blockDim.x) atomicAdd(&h[packed[j] & (LOCAL - 1)], 1);
  __syncthreads();
  int cnt = h[t];
  sd[t] = cnt;
  __syncthreads();
  int acc = cnt;
  for (int off = 1; off < LOCAL; off <<= 1) {
    int u = (t >= off) ? sd[t - off] : 0;
    __syncthreads();
    acc += u;
    sd[t] = acc;
    __syncthreads();
  }
  int myex = acc - cnt;
  int node = node0 + t;
  if (node < N) row_ptr[node] = beg + myex;
  h[t] = beg + myex;
  if (b == gridDim.x - 1 && t == 0) row_ptr[N] = E;
  __syncthreads();
  for (int j = beg + t; j < end; j += blockDim.x) {
    int v = packed[j];
    int p = atomicAdd(&h[v & (LOCAL - 1)], 1);
    ssrc[p] = v >> LBITS;
  }
}

// ---------------- dense transforms (thread-per-node, scalar weight loads) ----------------
__global__ __launch_bounds__(256) void gemm3_128x16(
    const float* __restrict__ x, const float* __restrict__ Wl, const float* __restrict__ Wr,
    const float* __restrict__ Wlin, const float* __restrict__ blin,
    __hip_bfloat16* __restrict__ XLh, float* __restrict__ XR, float* __restrict__ SK, int N) {
  int node = blockIdx.x * blockDim.x + threadIdx.x;
  if (node >= N) return;
  const float4* xr4 = (const float4*)(x + (size_t)node * F_IN);
  float al[16], ar[16], as_[16];
#pragma unroll
  for (int c = 0; c < 16; c++) {
    al[c] = 0.f;
    ar[c] = 0.f;
    as_[c] = 0.f;
  }
  for (int kk = 0; kk < F_IN / 4; kk++) {
    float4 xv = xr4[kk];
    float xs[4] = {xv.x, xv.y, xv.z, xv.w};
#pragma unroll
    for (int j = 0; j < 4; j++) {
      int k = kk * 4 + j;
#pragma unroll
      for (int c = 0; c < 16; c++) {
        al[c] = fmaf(xs[j], Wl[k * 16 + c], al[c]);
        ar[c] = fmaf(xs[j], Wr[k * 16 + c], ar[c]);
        as_[c] = fmaf(xs[j], Wlin[k * 16 + c], as_[c]);
      }
    }
  }
  unsigned int pk[8];
#pragma unroll
  for (int i = 0; i < 8; i++)
    pk[i] = (unsigned)f2bf(al[2 * i]) | ((unsigned)f2bf(al[2 * i + 1]) << 16);
  uint4* xlp = (uint4*)(XLh + (size_t)node * 16);
  xlp[0] = make_uint4(pk[0], pk[1], pk[2], pk[3]);
  xlp[1] = make_uint4(pk[4], pk[5], pk[6], pk[7]);
  float4* xrp = (float4*)(XR + (size_t)node * 16);
  float4* skp = (float4*)(SK + (size_t)node * 16);
#pragma unroll
  for (int q = 0; q < 4; q++) {
    xrp[q] = make_float4(ar[4 * q], ar[4 * q + 1], ar[4 * q + 2], ar[4 * q + 3]);
    skp[q] = make_float4(as_[4 * q] + blin[4 * q], as_[4 * q + 1] + blin[4 * q + 1],
                         as_[4 * q + 2] + blin[4 * q + 2], as_[4 * q + 3] + blin[4 * q + 3]);
  }
}

__global__ __launch_bounds__(256) void gemm3_16x8(
    const float* __restrict__ Hin, const float* __restrict__ Wl, const float* __restrict__ Wr,
    const float* __restrict__ Wlin, const float* __restrict__ blin,
    __hip_bfloat16* __restrict__ XLh, float* __restrict__ XR, float* __restrict__ SK, int N) {
  int node = blockIdx.x * blockDim.x + threadIdx.x;
  if (node >= N) return;
  const float4* hr4 = (const float4*)(Hin + (size_t)node * 16);
  float al[8], ar[8], as_[8];
#pragma unroll
  for (int c = 0; c < 8; c++) {
    al[c] = 0.f;
    ar[c] = 0.f;
    as_[c] = 0.f;
  }
#pragma unroll
  for (int kk = 0; kk < 4; kk++) {
    float4 hv = hr4[kk];
    float hs[4] = {hv.x, hv.y, hv.z, hv.w};
#pragma unroll
    for (int j = 0; j < 4; j++) {
      int k = kk * 4 + j;
#pragma unroll
      for (int c = 0; c < 8; c++) {
        al[c] = fmaf(hs[j], Wl[k * 8 + c], al[c]);
        ar[c] = fmaf(hs[j], Wr[k * 8 + c], ar[c]);
        as_[c] = fmaf(hs[j], Wlin[k * 8 + c], as_[c]);
      }
    }
  }
  unsigned int pk[4];
#pragma unroll
  for (int i = 0; i < 4; i++)
    pk[i] = (unsigned)f2bf(al[2 * i]) | ((unsigned)f2bf(al[2 * i + 1]) << 16);
  *(uint4*)(XLh + (size_t)node * 8) = make_uint4(pk[0], pk[1], pk[2], pk[3]);
  float4* xrp = (float4*)(XR + (size_t)node * 8);
  float4* skp = (float4*)(SK + (size_t)node * 8);
#pragma unroll
  for (int q = 0; q < 2; q++) {
    xrp[q] = make_float4(ar[4 * q], ar[4 * q + 1], ar[4 * q + 2], ar[4 * q + 3]);
    skp[q] = make_float4(as_[4 * q] + blin[4 * q], as_[4 * q + 1] + blin[4 * q + 1],
                         as_[4 * q + 2] + blin[4 * q + 2], as_[4 * q + 3] + blin[4 * q + 3]);
  }
}

// ---------------- GAT layer: 4-phase, shuffle-free scoring ----------------
// Phase S (edge-per-lane): gather source row to regs -> vpool; compute full
//   C-channel score in-lane (4-way ILP); p=exp(score) -> ppool. No shuffles.
// Phase D (group-per-node): vectorized ppool sum + ONE shuffle-reduce per node
//   -> invS0 in LDS.
// Phase 2 (channel-per-lane): LDS-only aggregation softmax, 2x unrolled.
// Overflow slots (>=POOL; P~1e-8) use slow global-recompute fallbacks.
template <int C, int POOL>
__global__ __launch_bounds__(256) void gat_layer(
    const __hip_bfloat16* __restrict__ XLh, const float* __restrict__ XR,
    const float* __restrict__ SK, const float* __restrict__ att, const float* __restrict__ bias,
    const float* __restrict__ tp, const int* __restrict__ row_ptr, const int* __restrict__ ssrc,
    float* __restrict__ H, int N) {
  constexpr int NPB = 256 / C;
  constexpr int LOGNPB = (NPB == 16) ? 4 : 5;
  __shared__ __align__(16) unsigned short vpool[POOL * C];
  __shared__ float ppool[POOL];
  __shared__ __align__(16) float xrl[NPB * C];
  __shared__ float invS0s[NPB];
  __shared__ int nb[NPB + 1];
  int t = threadIdx.x;
  int node0 = blockIdx.x * NPB;

  if (t <= NPB) {
    int nd = node0 + t;
    nb[t] = row_ptr[(nd < N) ? nd : N];
  }
  {
    size_t xi = (size_t)node0 * C + t;
    xrl[t] = (xi < (size_t)N * C) ? XR[xi] : 0.f;
  }
  float attr[C];
#pragma unroll
  for (int cc = 0; cc < C; cc++) attr[cc] = att[cc];
  float tval = tp[0];
  __syncthreads();

  int bbeg = nb[0];
  int nE = nb[NPB] - bbeg;
  int nCap = (nE < POOL) ? nE : POOL;
  const unsigned short* XLu = (const unsigned short*)XLh;

  // ---- Phase S: edge-per-lane gather + score ----
  for (int slot = t; slot < nCap; slot += 256) {
    // find owning node by binary search over nb
    int sb = slot + bbeg;
    int lo = 0, hi = NPB;
#pragma unroll
    for (int st = 0; st < LOGNPB; st++) {
      int mid = (lo + hi) >> 1;
      bool go = nb[mid] <= sb;
      lo = go ? mid : lo;
      hi = go ? hi : mid;
    }
    int g = lo;
    int s = ssrc[sb];
    float v[C];
    if constexpr (C == 16) {
      const uint4* gp = (const uint4*)(XLu + (size_t)s * 16);
      uint4 a = gp[0], b = gp[1];
      *(uint4*)&vpool[slot * 16] = a;
      *(uint4*)&vpool[slot * 16 + 8] = b;
      unsigned arr[8] = {a.x, a.y, a.z, a.w, b.x, b.y, b.z, b.w};
#pragma unroll
      for (int i = 0; i < 8; i++) {
        v[2 * i] = __uint_as_float(arr[i] << 16);
        v[2 * i + 1] = __uint_as_float(arr[i] & 0xffff0000u);
      }
    } else {
      const uint4* gp = (const uint4*)(XLu + (size_t)s * 8);
      uint4 a = gp[0];
      *(uint4*)&vpool[slot * 8] = a;
      unsigned arr[4] = {a.x, a.y, a.z, a.w};
#pragma unroll
      for (int i = 0; i < 4; i++) {
        v[2 * i] = __uint_as_float(arr[i] << 16);
        v[2 * i + 1] = __uint_as_float(arr[i] & 0xffff0000u);
      }
    }
    float xr[C];
    const float4* xp = (const float4*)&xrl[g * C];
#pragma unroll
    for (int q = 0; q < C / 4; q++) {
      float4 f = xp[q];
      xr[4 * q] = f.x;
      xr[4 * q + 1] = f.y;
      xr[4 * q + 2] = f.z;
      xr[4 * q + 3] = f.w;
    }
    float p0 = 0.f, p1 = 0.f, p2 = 0.f, p3 = 0.f;
#pragma unroll
    for (int cc = 0; cc < C; cc += 4) {
      float u0 = v[cc] + xr[cc];
      float u1 = v[cc + 1] + xr[cc + 1];
      float u2 = v[cc + 2] + xr[cc + 2];
      float u3 = v[cc + 3] + xr[cc + 3];
      p0 = fmaf(fmaxf(u0, 0.2f * u0), attr[cc], p0);
      p1 = fmaf(fmaxf(u1, 0.2f * u1), attr[cc + 1], p1);
      p2 = fmaf(fmaxf(u2, 0.2f * u2), attr[cc + 2], p2);
      p3 = fmaf(fmaxf(u3, 0.2f * u3), attr[cc + 3], p3);
    }
    ppool[slot] = __expf((p0 + p1) + (p2 + p3));
  }
  __syncthreads();

  int g = t / C;
  int c = t % C;
  int base = nb[g] - bbeg;
  int deg = nb[g + 1] - nb[g];
  int capd = POOL - base;
  capd = capd < 0 ? 0 : (capd > deg ? deg : capd);

  // ---- Phase D: S0 per node ----
  {
    float s0 = 0.f;
    for (int j = c; j < capd; j += C) s0 += ppool[base + j];
    for (int j = capd + c; j < deg; j += C) {  // overflow fallback (~never)
      int s = ssrc[bbeg + base + j];
      float sc = 0.f;
#pragma unroll
      for (int cc = 0; cc < C; cc++) {
        float v = __bfloat162float(XLh[(size_t)s * C + cc]);
        float u = v + xrl[g * C + cc];
        sc = fmaf(fmaxf(u, 0.2f * u), attr[cc], sc);
      }
      s0 += __expf(sc);
    }
#pragma unroll
    for (int m = 1; m < C; m <<= 1) s0 += __shfl_xor(s0, m, C);
    if (c == 0) invS0s[g] = (deg > 0) ? 1.0f / s0 : 0.f;
  }
  __syncthreads();

  // ---- Phase 2: aggregation softmax (LDS-only, 2x unrolled) ----
  float invS0 = invS0s[g];
  float S1 = 0.f, S2 = 0.f, S1b = 0.f, S2b = 0.f;
  int jj = 0;
  for (; jj + 2 <= capd; jj += 2) {
    int sl0 = base + jj;
    float v0 = __uint_as_float(((unsigned)vpool[sl0 * C + c]) << 16);
    float p0 = ppool[sl0];
    float v1 = __uint_as_float(((unsigned)vpool[(sl0 + 1) * C + c]) << 16);
    float p1 = ppool[sl0 + 1];
    float m0 = v0 * (p0 * invS0);
    float m1 = v1 * (p1 * invS0);
    float w0 = __expf(m0 * tval);
    float w1 = __expf(m1 * tval);
    S1 += w0;
    S2 = fmaf(w0, m0, S2);
    S1b += w1;
    S2b = fmaf(w1, m1, S2b);
  }
  for (; jj < capd; jj++) {
    int sl = base + jj;
    float v = __uint_as_float(((unsigned)vpool[sl * C + c]) << 16);
    float p = ppool[sl];
    float mm = v * (p * invS0);
    float w = __expf(mm * tval);
    S1 += w;
    S2 = fmaf(w, mm, S2);
  }
  for (; jj < deg; jj++) {  // overflow fallback (~never)
    int s = ssrc[bbeg + base + jj];
    float sc = 0.f, vc = 0.f;
#pragma unroll
    for (int cc = 0; cc < C; cc++) {
      float v = __bfloat162float(XLh[(size_t)s * C + cc]);
      if (cc == c) vc = v;
      float u = v + xrl[g * C + cc];
      sc = fmaf(fmaxf(u, 0.2f * u), attr[cc], sc);
    }
    float p = __expf(sc);
    float mm = vc * (p * invS0);
    float w = __expf(mm * tval);
    S1 += w;
    S2 = fmaf(w, mm, S2);
  }
  S1 += S1b;
  S2 += S2b;

  int node = node0 + g;
  if (node < N) {
    float gat = (deg > 0) ? (S2 / S1) : 0.f;
    float h = gat + bias[c] + SK[(size_t)node * C + c];
    H[(size_t)node * C + c] = fmaxf(h, 0.f);
  }
}

// ---------------- MLP head ----------------
__global__ void head_kernel(const float* __restrict__ H2,
                            const float* __restrict__ W3, const float* __restrict__ b3,
                            const float* __restrict__ W4, const float* __restrict__ b4,
                            const float* __restrict__ W5, const float* __restrict__ b5,
                            const float* __restrict__ Wout, const float* __restrict__ bout,
                            float* __restrict__ out, int N) {
  int i = blockIdx.x * blockDim.x + threadIdx.x;
  if (i >= N) return;
  const float4* h4 = (const float4*)(H2 + (size_t)i * 8);
  float4 ha = h4[0], hb = h4[1];
  float h[8] = {ha.x, ha.y, ha.z, ha.w, hb.x, hb.y, hb.z, hb.w};
  float s4 = 0.f;
#pragma unroll
  for (int cc = 0; cc < 8; cc++) {
    float z = b3[cc];
#pragma unroll
    for (int k = 0; k < 8; k++) z = fmaf(h[k], W3[k * 8 + cc], z);
    z = fmaxf(z, 0.f);
    s4 = fmaf(z, W4[cc], s4);
  }
  s4 = fmaxf(s4 + b4[0], 0.f);
  float s5 = fmaxf(fmaf(s4, W5[0], b5[0]), 0.f);
  float zo = fmaf(s5, Wout[0], bout[0]);
  float ls;
  if (zo >= 0.f)
    ls = -log1pf(expf(-zo));
  else
    ls = zo - log1pf(expf(zo));
  out[i] = ls;
}

extern "C" void kernel_launch(void* const* d_in, const int* in_sizes, int n_in,
                              void* d_out, int out_size, void* d_ws, size_t ws_size,
                              hipStream_t stream) {
  const float* x = (const float*)d_in[0];
  const int* ei = (const int*)d_in[1];
  const float* Wl1 = (const float*)d_in[3];
  const float* Wr1 = (const float*)d_in[4];
  const float* att1 = (const float*)d_in[5];
  const float* b1 = (const float*)d_in[6];
  const float* Wlin1 = (const float*)d_in[7];
  const float* blin1 = (const float*)d_in[8];
  const float* Wl2 = (const float*)d_in[9];
  const float* Wr2 = (const float*)d_in[10];
  const float* att2 = (const float*)d_in[11];
  const float* b2 = (const float*)d_in[12];
  const float* Wlin2 = (const float*)d_in[13];
  const float* blin2 = (const float*)d_in[14];
  const float* t = (const float*)d_in[15];
  const float* W3 = (const float*)d_in[16];
  const float* b3 = (const float*)d_in[17];
  const float* W4 = (const float*)d_in[18];
  const float* b4 = (const float*)d_in[19];
  const float* W5 = (const float*)d_in[20];
  const float* b5 = (const float*)d_in[21];
  const float* Wout = (const float*)d_in[22];
  const float* bout = (const float*)d_in[23];
  float* out = (float*)d_out;

  int N = in_sizes[0] / F_IN;
  int E = in_sizes[1] / 2;
  const int* src = ei;
  const int* dst = ei + E;
  int NB = (N + LOCAL - 1) >> LBITS;  // 391 for N=100000

  char* ws = (char*)d_ws;
  size_t off = 0;
  auto alloc = [&](size_t bytes) -> void* {
    void* p = ws + off;
    off = (off + bytes + 255) & ~(size_t)255;
    return p;
  };
  int* bcount = (int*)alloc((size_t)NB * 4);
  int* bbase = (int*)alloc((size_t)(NB + 1) * 4);
  int* bcursor = (int*)alloc((size_t)NB * 4);
  int* packed = (int*)alloc((size_t)E * 4);
  int* row_ptr = (int*)alloc((size_t)(N + 1) * 4);
  int* ssrc = (int*)alloc((size_t)E * 4);
  __hip_bfloat16* XL1 = (__hip_bfloat16*)alloc((size_t)N * C1 * 2);
  float* XR1 = (float*)alloc((size_t)N * C1 * 4);
  float* SK1 = (float*)alloc((size_t)N * C1 * 4);
  float* H1 = (float*)alloc((size_t)N * C1 * 4);
  __hip_bfloat16* XL2 = (__hip_bfloat16*)alloc((size_t)N * C2 * 2);
  float* XR2 = (float*)alloc((size_t)N * C2 * 4);
  float* SK2 = (float*)alloc((size_t)N * C2 * 4);
  float* H2 = (float*)alloc((size_t)N * C2 * 4);

  int nblkA = (E + 256 * ITEMS - 1) / (256 * ITEMS);

  hipMemsetAsync(bcount, 0, (size_t)NB * 4, stream);
  hipLaunchKernelGGL(bucket_hist, dim3(512), dim3(256), 0, stream, dst, bcount, E, NB);
  hipLaunchKernelGGL(bucket_scan, dim3(1), dim3(NB_MAX), 0, stream, bcount, bbase, bcursor, NB);
  hipLaunchKernelGGL(phaseA_lds, dim3(nblkA), dim3(256), 0, stream, src, dst, bcursor, packed, E,
                     NB);
  hipLaunchKernelGGL(phaseB_sort, dim3(NB), dim3(LOCAL), 0, stream, packed, bbase, row_ptr, ssrc, N,
                     E);
  hipLaunchKernelGGL(gemm3_128x16, dim3((N + 255) / 256), dim3(256), 0, stream, x, Wl1, Wr1,
                     Wlin1, blin1, XL1, XR1, SK1, N);
  hipLaunchKernelGGL((gat_layer<16, 640>), dim3((N + 15) / 16), dim3(256), 0, stream, XL1, XR1, SK1,
                     att1, b1, t, row_ptr, ssrc, H1, N);
  hipLaunchKernelGGL(gemm3_16x8, dim3((N + 255) / 256), dim3(256), 0, stream, H1, Wl2, Wr2,
                     Wlin2, blin2, XL2, XR2, SK2, N);
  hipLaunchKernelGGL((gat_layer<8, 1280>), dim3((N + 31) / 32), dim3(256), 0, stream, XL2, XR2, SK2,
                     att2, b2, t, row_ptr, ssrc, H2, N);
  hipLaunchKernelGGL(head_kernel, dim3((N + 255) / 256), dim3(256), 0, stream, H2, W3, b3, W4, b4,
                     W5, b5, Wout, bout, out, N);
}

// Round 8
// 345.941 us; speedup vs baseline: 3.7207x; 1.0283x over previous
//
#include <hip/hip_runtime.h>
#include <hip/hip_bf16.h>
#include <math.h>

#define F_IN 128
#define C1 16
#define C2 8

#define LBITS 8                 // 256 nodes per bucket
#define LOCAL (1 << LBITS)
#define NB_MAX 512              // supports N up to 131072
#define ITEMS 16                // edges per thread in phase A

static __device__ __forceinline__ unsigned short f2bf(float f) {
  __hip_bfloat16 h = __float2bfloat16(f);
  return *(unsigned short*)&h;
}

// ---------------- two-level bucket sort by dst ----------------
__global__ void bucket_hist(const int* __restrict__ dst, int* __restrict__ bcount, int E, int NB) {
  __shared__ int h[NB_MAX];
  for (int i = threadIdx.x; i < NB; i += blockDim.x) h[i] = 0;
  __syncthreads();
  int stride = gridDim.x * blockDim.x;
  for (int e = blockIdx.x * blockDim.x + threadIdx.x; e < E; e += stride)
    atomicAdd(&h[dst[e] >> LBITS], 1);
  __syncthreads();
  for (int i = threadIdx.x; i < NB; i += blockDim.x)
    if (h[i]) atomicAdd(&bcount[i], h[i]);
}

__global__ void bucket_scan(const int* __restrict__ bcount, int* __restrict__ bbase,
                            int* __restrict__ bcursor, int NB) {
  __shared__ int sd[NB_MAX];
  int t = threadIdx.x;
  int v = (t < NB) ? bcount[t] : 0;
  sd[t] = v;
  __syncthreads();
  int acc = v;
  for (int off = 1; off < NB_MAX; off <<= 1) {
    int u = (t >= off) ? sd[t - off] : 0;
    __syncthreads();
    acc += u;
    sd[t] = acc;
    __syncthreads();
  }
  if (t < NB) {
    int excl = acc - v;
    bbase[t] = excl;
    bcursor[t] = excl;
    if (t == NB - 1) bbase[NB] = acc;
  }
}

__global__ void phaseA_lds(const int* __restrict__ src, const int* __restrict__ dst,
                           int* __restrict__ bcursor, int* __restrict__ packed, int E, int NB) {
  __shared__ int hist[NB_MAX];
  __shared__ int cur[NB_MAX];
  for (int i = threadIdx.x; i < NB; i += blockDim.x) hist[i] = 0;
  __syncthreads();
  int base = blockIdx.x * blockDim.x * ITEMS;
  int vals[ITEMS];
  int bkt[ITEMS];
#pragma unroll
  for (int k = 0; k < ITEMS; k++) {
    int e = base + k * blockDim.x + threadIdx.x;
    if (e < E) {
      int s = src[e];
      int d = dst[e];
      bkt[k] = d >> LBITS;
      vals[k] = (s << LBITS) | (d & (LOCAL - 1));
      atomicAdd(&hist[bkt[k]], 1);
    } else {
      bkt[k] = -1;
    }
  }
  __syncthreads();
  for (int i = threadIdx.x; i < NB; i += blockDim.x) {
    int c = hist[i];
    cur[i] = c ? atomicAdd(&bcursor[i], c) : 0;
  }
  __syncthreads();
#pragma unroll
  for (int k = 0; k < ITEMS; k++) {
    if (bkt[k] >= 0) {
      int p = atomicAdd(&cur[bkt[k]], 1);
      packed[p] = vals[k];
    }
  }
}

__global__ void phaseB_sort(const int* __restrict__ packed, const int* __restrict__ bbase,
                            int* __restrict__ row_ptr, int* __restrict__ ssrc, int N, int E) {
  __shared__ int h[LOCAL];
  __shared__ int sd[LOCAL];
  int b = blockIdx.x;
  int t = threadIdx.x;  // blockDim.x == LOCAL == 256
  int beg = bbase[b], end = bbase[b + 1];
  int node0 = b << LBITS;
  h[t] = 0;
  __syncthreads();
  for (int j = beg + t; j < end; j += blockDim.x) atomicAdd(&h[packed[j] & (LOCAL - 1)], 1);
  __syncthreads();
  int cnt = h[t];
  sd[t] = cnt;
  __syncthreads();
  int acc = cnt;
  for (int off = 1; off < LOCAL; off <<= 1) {
    int u = (t >= off) ? sd[t - off] : 0;
    __syncthreads();
    acc += u;
    sd[t] = acc;
    __syncthreads();
  }
  int myex = acc - cnt;
  int node = node0 + t;
  if (node < N) row_ptr[node] = beg + myex;
  h[t] = beg + myex;
  if (b == gridDim.x - 1 && t == 0) row_ptr[N] = E;
  __syncthreads();
  for (int j = beg + t; j < end; j += blockDim.x) {
    int v = packed[j];
    int p = atomicAdd(&h[v & (LOCAL - 1)], 1);
    ssrc[p] = v >> LBITS;
  }
}

// ---------------- dense transforms (thread-per-node, full x-row register prefetch) ----------------
__global__ __launch_bounds__(256) void gemm3_128x16(
    const float* __restrict__ x, const float* __restrict__ Wl, const float* __restrict__ Wr,
    const float* __restrict__ Wlin, const float* __restrict__ blin,
    __hip_bfloat16* __restrict__ XLh, float* __restrict__ XR, float* __restrict__ SK, int N) {
  int node = blockIdx.x * blockDim.x + threadIdx.x;
  if (node >= N) return;
  const float4* xr4 = (const float4*)(x + (size_t)node * F_IN);
  // Prefetch the full 512B row: 32 independent dwordx4 loads in flight.
  float4 xv[32];
#pragma unroll
  for (int kk = 0; kk < 32; kk++) xv[kk] = xr4[kk];
  float al[16], ar[16], as_[16];
#pragma unroll
  for (int c = 0; c < 16; c++) {
    al[c] = 0.f;
    ar[c] = 0.f;
    as_[c] = 0.f;
  }
#pragma unroll
  for (int kk = 0; kk < 32; kk++) {
    float xs[4] = {xv[kk].x, xv[kk].y, xv[kk].z, xv[kk].w};
#pragma unroll
    for (int j = 0; j < 4; j++) {
      int k = kk * 4 + j;
#pragma unroll
      for (int c = 0; c < 16; c++) {
        al[c] = fmaf(xs[j], Wl[k * 16 + c], al[c]);
        ar[c] = fmaf(xs[j], Wr[k * 16 + c], ar[c]);
        as_[c] = fmaf(xs[j], Wlin[k * 16 + c], as_[c]);
      }
    }
  }
  unsigned int pk[8];
#pragma unroll
  for (int i = 0; i < 8; i++)
    pk[i] = (unsigned)f2bf(al[2 * i]) | ((unsigned)f2bf(al[2 * i + 1]) << 16);
  uint4* xlp = (uint4*)(XLh + (size_t)node * 16);
  xlp[0] = make_uint4(pk[0], pk[1], pk[2], pk[3]);
  xlp[1] = make_uint4(pk[4], pk[5], pk[6], pk[7]);
  float4* xrp = (float4*)(XR + (size_t)node * 16);
  float4* skp = (float4*)(SK + (size_t)node * 16);
#pragma unroll
  for (int q = 0; q < 4; q++) {
    xrp[q] = make_float4(ar[4 * q], ar[4 * q + 1], ar[4 * q + 2], ar[4 * q + 3]);
    skp[q] = make_float4(as_[4 * q] + blin[4 * q], as_[4 * q + 1] + blin[4 * q + 1],
                         as_[4 * q + 2] + blin[4 * q + 2], as_[4 * q + 3] + blin[4 * q + 3]);
  }
}

__global__ __launch_bounds__(256) void gemm3_16x8(
    const float* __restrict__ Hin, const float* __restrict__ Wl, const float* __restrict__ Wr,
    const float* __restrict__ Wlin, const float* __restrict__ blin,
    __hip_bfloat16* __restrict__ XLh, float* __restrict__ XR, float* __restrict__ SK, int N) {
  int node = blockIdx.x * blockDim.x + threadIdx.x;
  if (node >= N) return;
  const float4* hr4 = (const float4*)(Hin + (size_t)node * 16);
  float4 hv[4];
#pragma unroll
  for (int kk = 0; kk < 4; kk++) hv[kk] = hr4[kk];
  float al[8], ar[8], as_[8];
#pragma unroll
  for (int c = 0; c < 8; c++) {
    al[c] = 0.f;
    ar[c] = 0.f;
    as_[c] = 0.f;
  }
#pragma unroll
  for (int kk = 0; kk < 4; kk++) {
    float hs[4] = {hv[kk].x, hv[kk].y, hv[kk].z, hv[kk].w};
#pragma unroll
    for (int j = 0; j < 4; j++) {
      int k = kk * 4 + j;
#pragma unroll
      for (int c = 0; c < 8; c++) {
        al[c] = fmaf(hs[j], Wl[k * 8 + c], al[c]);
        ar[c] = fmaf(hs[j], Wr[k * 8 + c], ar[c]);
        as_[c] = fmaf(hs[j], Wlin[k * 8 + c], as_[c]);
      }
    }
  }
  unsigned int pk[4];
#pragma unroll
  for (int i = 0; i < 4; i++)
    pk[i] = (unsigned)f2bf(al[2 * i]) | ((unsigned)f2bf(al[2 * i + 1]) << 16);
  *(uint4*)(XLh + (size_t)node * 8) = make_uint4(pk[0], pk[1], pk[2], pk[3]);
  float4* xrp = (float4*)(XR + (size_t)node * 8);
  float4* skp = (float4*)(SK + (size_t)node * 8);
#pragma unroll
  for (int q = 0; q < 2; q++) {
    xrp[q] = make_float4(ar[4 * q], ar[4 * q + 1], ar[4 * q + 2], ar[4 * q + 3]);
    skp[q] = make_float4(as_[4 * q] + blin[4 * q], as_[4 * q + 1] + blin[4 * q + 1],
                         as_[4 * q + 2] + blin[4 * q + 2], as_[4 * q + 3] + blin[4 * q + 3]);
  }
}

// ---------------- GAT layer: 4-phase, shuffle-free scoring; optional fused MLP head ----------------
template <int C, int POOL, bool HEAD>
__global__ __launch_bounds__(256) void gat_layer(
    const __hip_bfloat16* __restrict__ XLh, const float* __restrict__ XR,
    const float* __restrict__ SK, const float* __restrict__ att, const float* __restrict__ bias,
    const float* __restrict__ tp, const int* __restrict__ row_ptr, const int* __restrict__ ssrc,
    float* __restrict__ H, int N,
    const float* __restrict__ W3, const float* __restrict__ b3, const float* __restrict__ W4,
    const float* __restrict__ b4, const float* __restrict__ W5, const float* __restrict__ b5,
    const float* __restrict__ Wout, const float* __restrict__ bout, float* __restrict__ out) {
  constexpr int NPB = 256 / C;
  constexpr int LOGNPB = (NPB == 16) ? 4 : 5;
  __shared__ __align__(16) unsigned short vpool[POOL * C];
  __shared__ float ppool[POOL];
  __shared__ __align__(16) float xrl[NPB * C];
  __shared__ float invS0s[NPB];
  __shared__ int nb[NPB + 1];
  __shared__ float hsh[HEAD ? NPB * C : 1];
  int t = threadIdx.x;
  int node0 = blockIdx.x * NPB;

  if (t <= NPB) {
    int nd = node0 + t;
    nb[t] = row_ptr[(nd < N) ? nd : N];
  }
  {
    size_t xi = (size_t)node0 * C + t;
    xrl[t] = (xi < (size_t)N * C) ? XR[xi] : 0.f;
  }
  float attr[C];
#pragma unroll
  for (int cc = 0; cc < C; cc++) attr[cc] = att[cc];
  float tval = tp[0];
  __syncthreads();

  int bbeg = nb[0];
  int nE = nb[NPB] - bbeg;
  int nCap = (nE < POOL) ? nE : POOL;
  const unsigned short* XLu = (const unsigned short*)XLh;

  // ---- Phase S: edge-per-lane gather + score ----
  for (int slot = t; slot < nCap; slot += 256) {
    int sb = slot + bbeg;
    int lo = 0, hi = NPB;
#pragma unroll
    for (int st = 0; st < LOGNPB; st++) {
      int mid = (lo + hi) >> 1;
      bool go = nb[mid] <= sb;
      lo = go ? mid : lo;
      hi = go ? hi : mid;
    }
    int g = lo;
    int s = ssrc[sb];
    float v[C];
    if constexpr (C == 16) {
      const uint4* gp = (const uint4*)(XLu + (size_t)s * 16);
      uint4 a = gp[0], b = gp[1];
      *(uint4*)&vpool[slot * 16] = a;
      *(uint4*)&vpool[slot * 16 + 8] = b;
      unsigned arr[8] = {a.x, a.y, a.z, a.w, b.x, b.y, b.z, b.w};
#pragma unroll
      for (int i = 0; i < 8; i++) {
        v[2 * i] = __uint_as_float(arr[i] << 16);
        v[2 * i + 1] = __uint_as_float(arr[i] & 0xffff0000u);
      }
    } else {
      const uint4* gp = (const uint4*)(XLu + (size_t)s * 8);
      uint4 a = gp[0];
      *(uint4*)&vpool[slot * 8] = a;
      unsigned arr[4] = {a.x, a.y, a.z, a.w};
#pragma unroll
      for (int i = 0; i < 4; i++) {
        v[2 * i] = __uint_as_float(arr[i] << 16);
        v[2 * i + 1] = __uint_as_float(arr[i] & 0xffff0000u);
      }
    }
    float xr[C];
    const float4* xp = (const float4*)&xrl[g * C];
#pragma unroll
    for (int q = 0; q < C / 4; q++) {
      float4 f = xp[q];
      xr[4 * q] = f.x;
      xr[4 * q + 1] = f.y;
      xr[4 * q + 2] = f.z;
      xr[4 * q + 3] = f.w;
    }
    float p0 = 0.f, p1 = 0.f, p2 = 0.f, p3 = 0.f;
#pragma unroll
    for (int cc = 0; cc < C; cc += 4) {
      float u0 = v[cc] + xr[cc];
      float u1 = v[cc + 1] + xr[cc + 1];
      float u2 = v[cc + 2] + xr[cc + 2];
      float u3 = v[cc + 3] + xr[cc + 3];
      p0 = fmaf(fmaxf(u0, 0.2f * u0), attr[cc], p0);
      p1 = fmaf(fmaxf(u1, 0.2f * u1), attr[cc + 1], p1);
      p2 = fmaf(fmaxf(u2, 0.2f * u2), attr[cc + 2], p2);
      p3 = fmaf(fmaxf(u3, 0.2f * u3), attr[cc + 3], p3);
    }
    ppool[slot] = __expf((p0 + p1) + (p2 + p3));
  }
  __syncthreads();

  int g = t / C;
  int c = t % C;
  int base = nb[g] - bbeg;
  int deg = nb[g + 1] - nb[g];
  int capd = POOL - base;
  capd = capd < 0 ? 0 : (capd > deg ? deg : capd);

  // ---- Phase D: S0 per node ----
  {
    float s0 = 0.f;
    for (int j = c; j < capd; j += C) s0 += ppool[base + j];
    for (int j = capd + c; j < deg; j += C) {  // overflow fallback (~never)
      int s = ssrc[bbeg + base + j];
      float sc = 0.f;
#pragma unroll
      for (int cc = 0; cc < C; cc++) {
        float v = __bfloat162float(XLh[(size_t)s * C + cc]);
        float u = v + xrl[g * C + cc];
        sc = fmaf(fmaxf(u, 0.2f * u), attr[cc], sc);
      }
      s0 += __expf(sc);
    }
#pragma unroll
    for (int m = 1; m < C; m <<= 1) s0 += __shfl_xor(s0, m, C);
    if (c == 0) invS0s[g] = (deg > 0) ? 1.0f / s0 : 0.f;
  }
  __syncthreads();

  // ---- Phase 2: aggregation softmax (LDS-only, 2x unrolled) ----
  float invS0 = invS0s[g];
  float S1 = 0.f, S2 = 0.f, S1b = 0.f, S2b = 0.f;
  int jj = 0;
  for (; jj + 2 <= capd; jj += 2) {
    int sl0 = base + jj;
    float v0 = __uint_as_float(((unsigned)vpool[sl0 * C + c]) << 16);
    float p0 = ppool[sl0];
    float v1 = __uint_as_float(((unsigned)vpool[(sl0 + 1) * C + c]) << 16);
    float p1 = ppool[sl0 + 1];
    float m0 = v0 * (p0 * invS0);
    float m1 = v1 * (p1 * invS0);
    float w0 = __expf(m0 * tval);
    float w1 = __expf(m1 * tval);
    S1 += w0;
    S2 = fmaf(w0, m0, S2);
    S1b += w1;
    S2b = fmaf(w1, m1, S2b);
  }
  for (; jj < capd; jj++) {
    int sl = base + jj;
    float v = __uint_as_float(((unsigned)vpool[sl * C + c]) << 16);
    float p = ppool[sl];
    float mm = v * (p * invS0);
    float w = __expf(mm * tval);
    S1 += w;
    S2 = fmaf(w, mm, S2);
  }
  for (; jj < deg; jj++) {  // overflow fallback (~never)
    int s = ssrc[bbeg + base + jj];
    float sc = 0.f, vc = 0.f;
#pragma unroll
    for (int cc = 0; cc < C; cc++) {
      float v = __bfloat162float(XLh[(size_t)s * C + cc]);
      if (cc == c) vc = v;
      float u = v + xrl[g * C + cc];
      sc = fmaf(fmaxf(u, 0.2f * u), attr[cc], sc);
    }
    float p = __expf(sc);
    float mm = vc * (p * invS0);
    float w = __expf(mm * tval);
    S1 += w;
    S2 = fmaf(w, mm, S2);
  }
  S1 += S1b;
  S2 += S2b;

  int node = node0 + g;
  bool valid = node < N;
  float hval = 0.f;
  if (valid) {
    float gat = (deg > 0) ? (S2 / S1) : 0.f;
    hval = fmaxf(gat + bias[c] + SK[(size_t)node * C + c], 0.f);
  }
  if constexpr (!HEAD) {
    if (valid) H[(size_t)node * C + c] = hval;
  } else {
    hsh[g * C + c] = hval;
    __syncthreads();
    if (t < NPB) {
      int nd = node0 + t;
      if (nd < N) {
        float h[8];
#pragma unroll
        for (int k = 0; k < 8; k++) h[k] = hsh[t * 8 + k];
        float s4 = 0.f;
#pragma unroll
        for (int cc = 0; cc < 8; cc++) {
          float z = b3[cc];
#pragma unroll
          for (int k = 0; k < 8; k++) z = fmaf(h[k], W3[k * 8 + cc], z);
          z = fmaxf(z, 0.f);
          s4 = fmaf(z, W4[cc], s4);
        }
        s4 = fmaxf(s4 + b4[0], 0.f);
        float s5 = fmaxf(fmaf(s4, W5[0], b5[0]), 0.f);
        float zo = fmaf(s5, Wout[0], bout[0]);
        float ls;
        if (zo >= 0.f)
          ls = -log1pf(expf(-zo));
        else
          ls = zo - log1pf(expf(zo));
        out[nd] = ls;
      }
    }
  }
}

extern "C" void kernel_launch(void* const* d_in, const int* in_sizes, int n_in,
                              void* d_out, int out_size, void* d_ws, size_t ws_size,
                              hipStream_t stream) {
  const float* x = (const float*)d_in[0];
  const int* ei = (const int*)d_in[1];
  const float* Wl1 = (const float*)d_in[3];
  const float* Wr1 = (const float*)d_in[4];
  const float* att1 = (const float*)d_in[5];
  const float* b1 = (const float*)d_in[6];
  const float* Wlin1 = (const float*)d_in[7];
  const float* blin1 = (const float*)d_in[8];
  const float* Wl2 = (const float*)d_in[9];
  const float* Wr2 = (const float*)d_in[10];
  const float* att2 = (const float*)d_in[11];
  const float* b2 = (const float*)d_in[12];
  const float* Wlin2 = (const float*)d_in[13];
  const float* blin2 = (const float*)d_in[14];
  const float* t = (const float*)d_in[15];
  const float* W3 = (const float*)d_in[16];
  const float* b3 = (const float*)d_in[17];
  const float* W4 = (const float*)d_in[18];
  const float* b4 = (const float*)d_in[19];
  const float* W5 = (const float*)d_in[20];
  const float* b5 = (const float*)d_in[21];
  const float* Wout = (const float*)d_in[22];
  const float* bout = (const float*)d_in[23];
  float* out = (float*)d_out;

  int N = in_sizes[0] / F_IN;
  int E = in_sizes[1] / 2;
  const int* src = ei;
  const int* dst = ei + E;
  int NB = (N + LOCAL - 1) >> LBITS;  // 391 for N=100000

  char* ws = (char*)d_ws;
  size_t off = 0;
  auto alloc = [&](size_t bytes) -> void* {
    void* p = ws + off;
    off = (off + bytes + 255) & ~(size_t)255;
    return p;
  };
  int* bcount = (int*)alloc((size_t)NB * 4);
  int* bbase = (int*)alloc((size_t)(NB + 1) * 4);
  int* bcursor = (int*)alloc((size_t)NB * 4);
  int* packed = (int*)alloc((size_t)E * 4);
  int* row_ptr = (int*)alloc((size_t)(N + 1) * 4);
  int* ssrc = (int*)alloc((size_t)E * 4);
  __hip_bfloat16* XL1 = (__hip_bfloat16*)alloc((size_t)N * C1 * 2);
  float* XR1 = (float*)alloc((size_t)N * C1 * 4);
  float* SK1 = (float*)alloc((size_t)N * C1 * 4);
  float* H1 = (float*)alloc((size_t)N * C1 * 4);
  __hip_bfloat16* XL2 = (__hip_bfloat16*)alloc((size_t)N * C2 * 2);
  float* XR2 = (float*)alloc((size_t)N * C2 * 4);
  float* SK2 = (float*)alloc((size_t)N * C2 * 4);

  int nblkA = (E + 256 * ITEMS - 1) / (256 * ITEMS);

  hipMemsetAsync(bcount, 0, (size_t)NB * 4, stream);
  hipLaunchKernelGGL(bucket_hist, dim3(512), dim3(256), 0, stream, dst, bcount, E, NB);
  hipLaunchKernelGGL(bucket_scan, dim3(1), dim3(NB_MAX), 0, stream, bcount, bbase, bcursor, NB);
  hipLaunchKernelGGL(phaseA_lds, dim3(nblkA), dim3(256), 0, stream, src, dst, bcursor, packed, E,
                     NB);
  hipLaunchKernelGGL(phaseB_sort, dim3(NB), dim3(LOCAL), 0, stream, packed, bbase, row_ptr, ssrc, N,
                     E);
  hipLaunchKernelGGL(gemm3_128x16, dim3((N + 255) / 256), dim3(256), 0, stream, x, Wl1, Wr1,
                     Wlin1, blin1, XL1, XR1, SK1, N);
  hipLaunchKernelGGL((gat_layer<16, 640, false>), dim3((N + 15) / 16), dim3(256), 0, stream, XL1,
                     XR1, SK1, att1, b1, t, row_ptr, ssrc, H1, N, nullptr, nullptr, nullptr,
                     nullptr, nullptr, nullptr, nullptr, nullptr, nullptr);
  hipLaunchKernelGGL(gemm3_16x8, dim3((N + 255) / 256), dim3(256), 0, stream, H1, Wl2, Wr2,
                     Wlin2, blin2, XL2, XR2, SK2, N);
  hipLaunchKernelGGL((gat_layer<8, 1280, true>), dim3((N + 31) / 32), dim3(256), 0, stream, XL2,
                     XR2, SK2, att2, b2, t, row_ptr, ssrc, nullptr, N, W3, b3, W4, b4, W5, b5, Wout,
                     bout, out);
}

// Round 9
// 319.880 us; speedup vs baseline: 4.0238x; 1.0815x over previous
//
#include <hip/hip_runtime.h>
#include <hip/hip_bf16.h>
#include <math.h>

#define F_IN 128
#define C1 16
#define C2 8

#define LBITS 8                 // 256 nodes per bucket
#define LOCAL (1 << LBITS)
#define NB_MAX 512              // supports N up to 131072
#define ITEMS 16                // edges per thread in phase A

static __device__ __forceinline__ unsigned short f2bf(float f) {
  __hip_bfloat16 h = __float2bfloat16(f);
  return *(unsigned short*)&h;
}

// ---------------- two-level bucket sort by dst ----------------
__global__ void bucket_hist(const int* __restrict__ dst, int* __restrict__ bcount, int E, int NB) {
  __shared__ int h[NB_MAX];
  for (int i = threadIdx.x; i < NB; i += blockDim.x) h[i] = 0;
  __syncthreads();
  int stride = gridDim.x * blockDim.x;
  for (int e = blockIdx.x * blockDim.x + threadIdx.x; e < E; e += stride)
    atomicAdd(&h[dst[e] >> LBITS], 1);
  __syncthreads();
  for (int i = threadIdx.x; i < NB; i += blockDim.x)
    if (h[i]) atomicAdd(&bcount[i], h[i]);
}

__global__ void bucket_scan(const int* __restrict__ bcount, int* __restrict__ bbase,
                            int* __restrict__ bcursor, int NB) {
  __shared__ int sd[NB_MAX];
  int t = threadIdx.x;
  int v = (t < NB) ? bcount[t] : 0;
  sd[t] = v;
  __syncthreads();
  int acc = v;
  for (int off = 1; off < NB_MAX; off <<= 1) {
    int u = (t >= off) ? sd[t - off] : 0;
    __syncthreads();
    acc += u;
    sd[t] = acc;
    __syncthreads();
  }
  if (t < NB) {
    int excl = acc - v;
    bbase[t] = excl;
    bcursor[t] = excl;
    if (t == NB - 1) bbase[NB] = acc;
  }
}

__global__ void phaseA_lds(const int* __restrict__ src, const int* __restrict__ dst,
                           int* __restrict__ bcursor, int* __restrict__ packed, int E, int NB) {
  __shared__ int hist[NB_MAX];
  __shared__ int cur[NB_MAX];
  for (int i = threadIdx.x; i < NB; i += blockDim.x) hist[i] = 0;
  __syncthreads();
  int base = blockIdx.x * blockDim.x * ITEMS;
  int vals[ITEMS];
  int bkt[ITEMS];
#pragma unroll
  for (int k = 0; k < ITEMS; k++) {
    int e = base + k * blockDim.x + threadIdx.x;
    if (e < E) {
      int s = src[e];
      int d = dst[e];
      bkt[k] = d >> LBITS;
      vals[k] = (s << LBITS) | (d & (LOCAL - 1));
      atomicAdd(&hist[bkt[k]], 1);
    } else {
      bkt[k] = -1;
    }
  }
  __syncthreads();
  for (int i = threadIdx.x; i < NB; i += blockDim.x) {
    int c = hist[i];
    cur[i] = c ? atomicAdd(&bcursor[i], c) : 0;
  }
  __syncthreads();
#pragma unroll
  for (int k = 0; k < ITEMS; k++) {
    if (bkt[k] >= 0) {
      int p = atomicAdd(&cur[bkt[k]], 1);
      packed[p] = vals[k];
    }
  }
}

__global__ void phaseB_sort(const int* __restrict__ packed, const int* __restrict__ bbase,
                            int* __restrict__ row_ptr, int* __restrict__ ssrc, int N, int E) {
  __shared__ int h[LOCAL];
  __shared__ int sd[LOCAL];
  int b = blockIdx.x;
  int t = threadIdx.x;  // blockDim.x == LOCAL == 256
  int beg = bbase[b], end = bbase[b + 1];
  int node0 = b << LBITS;
  h[t] = 0;
  __syncthreads();
  for (int j = beg + t; j < end; j += blockDim.x) atomicAdd(&h[packed[j] & (LOCAL - 1)], 1);
  __syncthreads();
  int cnt = h[t];
  sd[t] = cnt;
  __syncthreads();
  int acc = cnt;
  for (int off = 1; off < LOCAL; off <<= 1) {
    int u = (t >= off) ? sd[t - off] : 0;
    __syncthreads();
    acc += u;
    sd[t] = acc;
    __syncthreads();
  }
  int myex = acc - cnt;
  int node = node0 + t;
  if (node < N) row_ptr[node] = beg + myex;
  h[t] = beg + myex;
  if (b == gridDim.x - 1 && t == 0) row_ptr[N] = E;
  __syncthreads();
  for (int j = beg + t; j < end; j += blockDim.x) {
    int v = packed[j];
    int p = atomicAdd(&h[v & (LOCAL - 1)], 1);
    ssrc[p] = v >> LBITS;
  }
}

// ---------------- dense transforms: matrix-split (blockIdx.x % 3) ----------------
// 3x the waves of thread-per-node, 16 accumulators, 8KB weight stream per wave.
// Consecutive blocks share x rows -> L2/L3 serve repeats.
__global__ __launch_bounds__(256) void gemm3_128x16(
    const float* __restrict__ x, const float* __restrict__ Wl, const float* __restrict__ Wr,
    const float* __restrict__ Wlin, const float* __restrict__ blin,
    __hip_bfloat16* __restrict__ XLh, float* __restrict__ XR, float* __restrict__ SK, int N) {
  int bx = blockIdx.x;
  int mat = bx % 3;
  int node = (bx / 3) * 256 + threadIdx.x;
  if (node >= N) return;
  const float* __restrict__ W = (mat == 0) ? Wl : (mat == 1) ? Wr : Wlin;
  const float4* xr4 = (const float4*)(x + (size_t)node * F_IN);
  float acc[16];
#pragma unroll
  for (int c = 0; c < 16; c++) acc[c] = 0.f;
#pragma unroll 8
  for (int kk = 0; kk < F_IN / 4; kk++) {
    float4 xv = xr4[kk];
    float xs[4] = {xv.x, xv.y, xv.z, xv.w};
#pragma unroll
    for (int j = 0; j < 4; j++) {
      int k = kk * 4 + j;
#pragma unroll
      for (int c = 0; c < 16; c++) acc[c] = fmaf(xs[j], W[k * 16 + c], acc[c]);
    }
  }
  if (mat == 0) {
    unsigned int pk[8];
#pragma unroll
    for (int i = 0; i < 8; i++)
      pk[i] = (unsigned)f2bf(acc[2 * i]) | ((unsigned)f2bf(acc[2 * i + 1]) << 16);
    uint4* xlp = (uint4*)(XLh + (size_t)node * 16);
    xlp[0] = make_uint4(pk[0], pk[1], pk[2], pk[3]);
    xlp[1] = make_uint4(pk[4], pk[5], pk[6], pk[7]);
  } else if (mat == 1) {
    float4* xrp = (float4*)(XR + (size_t)node * 16);
#pragma unroll
    for (int q = 0; q < 4; q++)
      xrp[q] = make_float4(acc[4 * q], acc[4 * q + 1], acc[4 * q + 2], acc[4 * q + 3]);
  } else {
    float4* skp = (float4*)(SK + (size_t)node * 16);
#pragma unroll
    for (int q = 0; q < 4; q++)
      skp[q] = make_float4(acc[4 * q] + blin[4 * q], acc[4 * q + 1] + blin[4 * q + 1],
                           acc[4 * q + 2] + blin[4 * q + 2], acc[4 * q + 3] + blin[4 * q + 3]);
  }
}

__global__ __launch_bounds__(256) void gemm3_16x8(
    const float* __restrict__ Hin, const float* __restrict__ Wl, const float* __restrict__ Wr,
    const float* __restrict__ Wlin, const float* __restrict__ blin,
    __hip_bfloat16* __restrict__ XLh, float* __restrict__ XR, float* __restrict__ SK, int N) {
  int bx = blockIdx.x;
  int mat = bx % 3;
  int node = (bx / 3) * 256 + threadIdx.x;
  if (node >= N) return;
  const float* __restrict__ W = (mat == 0) ? Wl : (mat == 1) ? Wr : Wlin;
  const float4* hr4 = (const float4*)(Hin + (size_t)node * 16);
  float acc[8];
#pragma unroll
  for (int c = 0; c < 8; c++) acc[c] = 0.f;
#pragma unroll
  for (int kk = 0; kk < 4; kk++) {
    float4 hv = hr4[kk];
    float hs[4] = {hv.x, hv.y, hv.z, hv.w};
#pragma unroll
    for (int j = 0; j < 4; j++) {
      int k = kk * 4 + j;
#pragma unroll
      for (int c = 0; c < 8; c++) acc[c] = fmaf(hs[j], W[k * 8 + c], acc[c]);
    }
  }
  if (mat == 0) {
    unsigned int pk[4];
#pragma unroll
    for (int i = 0; i < 4; i++)
      pk[i] = (unsigned)f2bf(acc[2 * i]) | ((unsigned)f2bf(acc[2 * i + 1]) << 16);
    *(uint4*)(XLh + (size_t)node * 8) = make_uint4(pk[0], pk[1], pk[2], pk[3]);
  } else if (mat == 1) {
    float4* xrp = (float4*)(XR + (size_t)node * 8);
#pragma unroll
    for (int q = 0; q < 2; q++)
      xrp[q] = make_float4(acc[4 * q], acc[4 * q + 1], acc[4 * q + 2], acc[4 * q + 3]);
  } else {
    float4* skp = (float4*)(SK + (size_t)node * 8);
#pragma unroll
    for (int q = 0; q < 2; q++)
      skp[q] = make_float4(acc[4 * q] + blin[4 * q], acc[4 * q + 1] + blin[4 * q + 1],
                           acc[4 * q + 2] + blin[4 * q + 2], acc[4 * q + 3] + blin[4 * q + 3]);
  }
}

// ---------------- GAT layer: 4-phase, shuffle-free scoring; optional fused MLP head ----------------
template <int C, int POOL, bool HEAD>
__global__ __launch_bounds__(256) void gat_layer(
    const __hip_bfloat16* __restrict__ XLh, const float* __restrict__ XR,
    const float* __restrict__ SK, const float* __restrict__ att, const float* __restrict__ bias,
    const float* __restrict__ tp, const int* __restrict__ row_ptr, const int* __restrict__ ssrc,
    float* __restrict__ H, int N,
    const float* __restrict__ W3, const float* __restrict__ b3, const float* __restrict__ W4,
    const float* __restrict__ b4, const float* __restrict__ W5, const float* __restrict__ b5,
    const float* __restrict__ Wout, const float* __restrict__ bout, float* __restrict__ out) {
  constexpr int NPB = 256 / C;
  constexpr int LOGNPB = (NPB == 16) ? 4 : 5;
  __shared__ __align__(16) unsigned short vpool[POOL * C];
  __shared__ float ppool[POOL];
  __shared__ __align__(16) float xrl[NPB * C];
  __shared__ float invS0s[NPB];
  __shared__ int nb[NPB + 1];
  __shared__ float hsh[HEAD ? NPB * C : 1];
  int t = threadIdx.x;
  int node0 = blockIdx.x * NPB;

  if (t <= NPB) {
    int nd = node0 + t;
    nb[t] = row_ptr[(nd < N) ? nd : N];
  }
  {
    size_t xi = (size_t)node0 * C + t;
    xrl[t] = (xi < (size_t)N * C) ? XR[xi] : 0.f;
  }
  float attr[C];
#pragma unroll
  for (int cc = 0; cc < C; cc++) attr[cc] = att[cc];
  float tval = tp[0];
  __syncthreads();

  int bbeg = nb[0];
  int nE = nb[NPB] - bbeg;
  int nCap = (nE < POOL) ? nE : POOL;
  const unsigned short* XLu = (const unsigned short*)XLh;

  // ---- Phase S: edge-per-lane gather + score ----
  for (int slot = t; slot < nCap; slot += 256) {
    int sb = slot + bbeg;
    int lo = 0, hi = NPB;
#pragma unroll
    for (int st = 0; st < LOGNPB; st++) {
      int mid = (lo + hi) >> 1;
      bool go = nb[mid] <= sb;
      lo = go ? mid : lo;
      hi = go ? hi : mid;
    }
    int g = lo;
    int s = ssrc[sb];
    float v[C];
    if constexpr (C == 16) {
      const uint4* gp = (const uint4*)(XLu + (size_t)s * 16);
      uint4 a = gp[0], b = gp[1];
      *(uint4*)&vpool[slot * 16] = a;
      *(uint4*)&vpool[slot * 16 + 8] = b;
      unsigned arr[8] = {a.x, a.y, a.z, a.w, b.x, b.y, b.z, b.w};
#pragma unroll
      for (int i = 0; i < 8; i++) {
        v[2 * i] = __uint_as_float(arr[i] << 16);
        v[2 * i + 1] = __uint_as_float(arr[i] & 0xffff0000u);
      }
    } else {
      const uint4* gp = (const uint4*)(XLu + (size_t)s * 8);
      uint4 a = gp[0];
      *(uint4*)&vpool[slot * 8] = a;
      unsigned arr[4] = {a.x, a.y, a.z, a.w};
#pragma unroll
      for (int i = 0; i < 4; i++) {
        v[2 * i] = __uint_as_float(arr[i] << 16);
        v[2 * i + 1] = __uint_as_float(arr[i] & 0xffff0000u);
      }
    }
    float xr[C];
    const float4* xp = (const float4*)&xrl[g * C];
#pragma unroll
    for (int q = 0; q < C / 4; q++) {
      float4 f = xp[q];
      xr[4 * q] = f.x;
      xr[4 * q + 1] = f.y;
      xr[4 * q + 2] = f.z;
      xr[4 * q + 3] = f.w;
    }
    float p0 = 0.f, p1 = 0.f, p2 = 0.f, p3 = 0.f;
#pragma unroll
    for (int cc = 0; cc < C; cc += 4) {
      float u0 = v[cc] + xr[cc];
      float u1 = v[cc + 1] + xr[cc + 1];
      float u2 = v[cc + 2] + xr[cc + 2];
      float u3 = v[cc + 3] + xr[cc + 3];
      p0 = fmaf(fmaxf(u0, 0.2f * u0), attr[cc], p0);
      p1 = fmaf(fmaxf(u1, 0.2f * u1), attr[cc + 1], p1);
      p2 = fmaf(fmaxf(u2, 0.2f * u2), attr[cc + 2], p2);
      p3 = fmaf(fmaxf(u3, 0.2f * u3), attr[cc + 3], p3);
    }
    ppool[slot] = __expf((p0 + p1) + (p2 + p3));
  }
  __syncthreads();

  int g = t / C;
  int c = t % C;
  int base = nb[g] - bbeg;
  int deg = nb[g + 1] - nb[g];
  int capd = POOL - base;
  capd = capd < 0 ? 0 : (capd > deg ? deg : capd);

  // ---- Phase D: S0 per node ----
  {
    float s0 = 0.f;
    for (int j = c; j < capd; j += C) s0 += ppool[base + j];
    for (int j = capd + c; j < deg; j += C) {  // overflow fallback (~never)
      int s = ssrc[bbeg + base + j];
      float sc = 0.f;
#pragma unroll
      for (int cc = 0; cc < C; cc++) {
        float v = __bfloat162float(XLh[(size_t)s * C + cc]);
        float u = v + xrl[g * C + cc];
        sc = fmaf(fmaxf(u, 0.2f * u), attr[cc], sc);
      }
      s0 += __expf(sc);
    }
#pragma unroll
    for (int m = 1; m < C; m <<= 1) s0 += __shfl_xor(s0, m, C);
    if (c == 0) invS0s[g] = (deg > 0) ? 1.0f / s0 : 0.f;
  }
  __syncthreads();

  // ---- Phase 2: aggregation softmax (LDS-only, 2x unrolled) ----
  float invS0 = invS0s[g];
  float S1 = 0.f, S2 = 0.f, S1b = 0.f, S2b = 0.f;
  int jj = 0;
  for (; jj + 2 <= capd; jj += 2) {
    int sl0 = base + jj;
    float v0 = __uint_as_float(((unsigned)vpool[sl0 * C + c]) << 16);
    float p0 = ppool[sl0];
    float v1 = __uint_as_float(((unsigned)vpool[(sl0 + 1) * C + c]) << 16);
    float p1 = ppool[sl0 + 1];
    float m0 = v0 * (p0 * invS0);
    float m1 = v1 * (p1 * invS0);
    float w0 = __expf(m0 * tval);
    float w1 = __expf(m1 * tval);
    S1 += w0;
    S2 = fmaf(w0, m0, S2);
    S1b += w1;
    S2b = fmaf(w1, m1, S2b);
  }
  for (; jj < capd; jj++) {
    int sl = base + jj;
    float v = __uint_as_float(((unsigned)vpool[sl * C + c]) << 16);
    float p = ppool[sl];
    float mm = v * (p * invS0);
    float w = __expf(mm * tval);
    S1 += w;
    S2 = fmaf(w, mm, S2);
  }
  for (; jj < deg; jj++) {  // overflow fallback (~never)
    int s = ssrc[bbeg + base + jj];
    float sc = 0.f, vc = 0.f;
#pragma unroll
    for (int cc = 0; cc < C; cc++) {
      float v = __bfloat162float(XLh[(size_t)s * C + cc]);
      if (cc == c) vc = v;
      float u = v + xrl[g * C + cc];
      sc = fmaf(fmaxf(u, 0.2f * u), attr[cc], sc);
    }
    float p = __expf(sc);
    float mm = vc * (p * invS0);
    float w = __expf(mm * tval);
    S1 += w;
    S2 = fmaf(w, mm, S2);
  }
  S1 += S1b;
  S2 += S2b;

  int node = node0 + g;
  bool valid = node < N;
  float hval = 0.f;
  if (valid) {
    float gat = (deg > 0) ? (S2 / S1) : 0.f;
    hval = fmaxf(gat + bias[c] + SK[(size_t)node * C + c], 0.f);
  }
  if constexpr (!HEAD) {
    if (valid) H[(size_t)node * C + c] = hval;
  } else {
    hsh[g * C + c] = hval;
    __syncthreads();
    if (t < NPB) {
      int nd = node0 + t;
      if (nd < N) {
        float h[8];
#pragma unroll
        for (int k = 0; k < 8; k++) h[k] = hsh[t * 8 + k];
        float s4 = 0.f;
#pragma unroll
        for (int cc = 0; cc < 8; cc++) {
          float z = b3[cc];
#pragma unroll
          for (int k = 0; k < 8; k++) z = fmaf(h[k], W3[k * 8 + cc], z);
          z = fmaxf(z, 0.f);
          s4 = fmaf(z, W4[cc], s4);
        }
        s4 = fmaxf(s4 + b4[0], 0.f);
        float s5 = fmaxf(fmaf(s4, W5[0], b5[0]), 0.f);
        float zo = fmaf(s5, Wout[0], bout[0]);
        float ls;
        if (zo >= 0.f)
          ls = -log1pf(expf(-zo));
        else
          ls = zo - log1pf(expf(zo));
        out[nd] = ls;
      }
    }
  }
}

extern "C" void kernel_launch(void* const* d_in, const int* in_sizes, int n_in,
                              void* d_out, int out_size, void* d_ws, size_t ws_size,
                              hipStream_t stream) {
  const float* x = (const float*)d_in[0];
  const int* ei = (const int*)d_in[1];
  const float* Wl1 = (const float*)d_in[3];
  const float* Wr1 = (const float*)d_in[4];
  const float* att1 = (const float*)d_in[5];
  const float* b1 = (const float*)d_in[6];
  const float* Wlin1 = (const float*)d_in[7];
  const float* blin1 = (const float*)d_in[8];
  const float* Wl2 = (const float*)d_in[9];
  const float* Wr2 = (const float*)d_in[10];
  const float* att2 = (const float*)d_in[11];
  const float* b2 = (const float*)d_in[12];
  const float* Wlin2 = (const float*)d_in[13];
  const float* blin2 = (const float*)d_in[14];
  const float* t = (const float*)d_in[15];
  const float* W3 = (const float*)d_in[16];
  const float* b3 = (const float*)d_in[17];
  const float* W4 = (const float*)d_in[18];
  const float* b4 = (const float*)d_in[19];
  const float* W5 = (const float*)d_in[20];
  const float* b5 = (const float*)d_in[21];
  const float* Wout = (const float*)d_in[22];
  const float* bout = (const float*)d_in[23];
  float* out = (float*)d_out;

  int N = in_sizes[0] / F_IN;
  int E = in_sizes[1] / 2;
  const int* src = ei;
  const int* dst = ei + E;
  int NB = (N + LOCAL - 1) >> LBITS;  // 391 for N=100000

  char* ws = (char*)d_ws;
  size_t off = 0;
  auto alloc = [&](size_t bytes) -> void* {
    void* p = ws + off;
    off = (off + bytes + 255) & ~(size_t)255;
    return p;
  };
  int* bcount = (int*)alloc((size_t)NB * 4);
  int* bbase = (int*)alloc((size_t)(NB + 1) * 4);
  int* bcursor = (int*)alloc((size_t)NB * 4);
  int* packed = (int*)alloc((size_t)E * 4);
  int* row_ptr = (int*)alloc((size_t)(N + 1) * 4);
  int* ssrc = (int*)alloc((size_t)E * 4);
  __hip_bfloat16* XL1 = (__hip_bfloat16*)alloc((size_t)N * C1 * 2);
  float* XR1 = (float*)alloc((size_t)N * C1 * 4);
  float* SK1 = (float*)alloc((size_t)N * C1 * 4);
  float* H1 = (float*)alloc((size_t)N * C1 * 4);
  __hip_bfloat16* XL2 = (__hip_bfloat16*)alloc((size_t)N * C2 * 2);
  float* XR2 = (float*)alloc((size_t)N * C2 * 4);
  float* SK2 = (float*)alloc((size_t)N * C2 * 4);

  int nblkA = (E + 256 * ITEMS - 1) / (256 * ITEMS);
  int nodeBlk = (N + 255) / 256;  // 391

  hipMemsetAsync(bcount, 0, (size_t)NB * 4, stream);
  hipLaunchKernelGGL(bucket_hist, dim3(512), dim3(256), 0, stream, dst, bcount, E, NB);
  hipLaunchKernelGGL(bucket_scan, dim3(1), dim3(NB_MAX), 0, stream, bcount, bbase, bcursor, NB);
  hipLaunchKernelGGL(phaseA_lds, dim3(nblkA), dim3(256), 0, stream, src, dst, bcursor, packed, E,
                     NB);
  hipLaunchKernelGGL(phaseB_sort, dim3(NB), dim3(LOCAL), 0, stream, packed, bbase, row_ptr, ssrc, N,
                     E);
  hipLaunchKernelGGL(gemm3_128x16, dim3(nodeBlk * 3), dim3(256), 0, stream, x, Wl1, Wr1,
                     Wlin1, blin1, XL1, XR1, SK1, N);
  hipLaunchKernelGGL((gat_layer<16, 640, false>), dim3((N + 15) / 16), dim3(256), 0, stream, XL1,
                     XR1, SK1, att1, b1, t, row_ptr, ssrc, H1, N, nullptr, nullptr, nullptr,
                     nullptr, nullptr, nullptr, nullptr, nullptr, nullptr);
  hipLaunchKernelGGL(gemm3_16x8, dim3(nodeBlk * 3), dim3(256), 0, stream, H1, Wl2, Wr2,
                     Wlin2, blin2, XL2, XR2, SK2, N);
  hipLaunchKernelGGL((gat_layer<8, 1280, true>), dim3((N + 31) / 32), dim3(256), 0, stream, XL2,
                     XR2, SK2, att2, b2, t, row_ptr, ssrc, nullptr, N, W3, b3, W4, b4, W5, b5, Wout,
                     bout, out);
}

// Round 10
// 309.876 us; speedup vs baseline: 4.1537x; 1.0323x over previous
//
#include <hip/hip_runtime.h>
#include <hip/hip_bf16.h>
#include <math.h>

#define F_IN 128
#define C1 16
#define C2 8

#define LBITS 8                 // 256 nodes per bucket
#define LOCAL (1 << LBITS)
#define NB_MAX 512              // supports N up to 131072
#define ITEMS 16                // edges per thread in phase A
#define EPB (256 * ITEMS)       // 4096 edges per phase-A block

static __device__ __forceinline__ unsigned short f2bf(float f) {
  __hip_bfloat16 h = __float2bfloat16(f);
  return *(unsigned short*)&h;
}

// ---------------- two-level bucket sort by dst ----------------
__global__ void bucket_hist(const int* __restrict__ dst, int* __restrict__ bcount, int E, int NB) {
  __shared__ int h[NB_MAX];
  for (int i = threadIdx.x; i < NB; i += blockDim.x) h[i] = 0;
  __syncthreads();
  int stride = gridDim.x * blockDim.x;
  for (int e = blockIdx.x * blockDim.x + threadIdx.x; e < E; e += stride)
    atomicAdd(&h[dst[e] >> LBITS], 1);
  __syncthreads();
  for (int i = threadIdx.x; i < NB; i += blockDim.x)
    if (h[i]) atomicAdd(&bcount[i], h[i]);
}

__global__ void bucket_scan(const int* __restrict__ bcount, int* __restrict__ bbase,
                            int* __restrict__ bcursor, int NB) {
  __shared__ int sd[NB_MAX];
  int t = threadIdx.x;
  int v = (t < NB) ? bcount[t] : 0;
  sd[t] = v;
  __syncthreads();
  int acc = v;
  for (int off = 1; off < NB_MAX; off <<= 1) {
    int u = (t >= off) ? sd[t - off] : 0;
    __syncthreads();
    acc += u;
    sd[t] = acc;
    __syncthreads();
  }
  if (t < NB) {
    int excl = acc - v;
    bbase[t] = excl;
    bcursor[t] = excl;
    if (t == NB - 1) bbase[NB] = acc;
  }
}

// Phase A: block-local counting sort into LDS stage, then coalesced sweep to global.
__global__ __launch_bounds__(256) void phaseA_lds(const int* __restrict__ src,
                                                  const int* __restrict__ dst,
                                                  int* __restrict__ bcursor,
                                                  int* __restrict__ packed, int E, int NB) {
  __shared__ int hist[NB_MAX];    // counts -> local cursor
  __shared__ int lbase[NB_MAX];   // local exclusive prefix
  __shared__ int gbase[NB_MAX];   // reserved global chunk base
  __shared__ int sdata[256];
  __shared__ int stage[EPB];
  __shared__ unsigned short stageb[EPB];
  int t = threadIdx.x;
  for (int i = t; i < NB; i += 256) hist[i] = 0;
  __syncthreads();
  int base = blockIdx.x * EPB;
  int vals[ITEMS];
  int bkt[ITEMS];
#pragma unroll
  for (int k = 0; k < ITEMS; k++) {
    int e = base + k * 256 + t;
    if (e < E) {
      int s = src[e];
      int d = dst[e];
      bkt[k] = d >> LBITS;
      vals[k] = (s << LBITS) | (d & (LOCAL - 1));
      atomicAdd(&hist[bkt[k]], 1);
    } else {
      bkt[k] = -1;
    }
  }
  __syncthreads();
  // block-wide exclusive scan over hist[0..NB) (NB <= 512): 2 entries/thread
  int i0 = 2 * t, i1 = 2 * t + 1;
  int h0 = (i0 < NB) ? hist[i0] : 0;
  int h1 = (i1 < NB) ? hist[i1] : 0;
  int s2 = h0 + h1;
  sdata[t] = s2;
  __syncthreads();
  int acc = s2;
  for (int off = 1; off < 256; off <<= 1) {
    int u = (t >= off) ? sdata[t - off] : 0;
    __syncthreads();
    acc += u;
    sdata[t] = acc;
    __syncthreads();
  }
  int excl = acc - s2;
  if (i0 < NB) lbase[i0] = excl;
  if (i1 < NB) lbase[i1] = excl + h0;
  __syncthreads();
  // reserve global chunks; re-init hist as local cursor
  for (int i = t; i < NB; i += 256) {
    int c = hist[i];
    gbase[i] = c ? atomicAdd(&bcursor[i], c) : 0;
    hist[i] = lbase[i];
  }
  __syncthreads();
  // scatter into LDS stage
#pragma unroll
  for (int k = 0; k < ITEMS; k++) {
    if (bkt[k] >= 0) {
      int lp = atomicAdd(&hist[bkt[k]], 1);
      stage[lp] = vals[k];
      stageb[lp] = (unsigned short)bkt[k];
    }
  }
  __syncthreads();
  // coalesced sweep to global
  int blockE = E - base;
  if (blockE > EPB) blockE = EPB;
  for (int i = t; i < blockE; i += 256) {
    int b = stageb[i];
    packed[gbase[b] + (i - lbase[b])] = stage[i];
  }
}

__global__ void phaseB_sort(const int* __restrict__ packed, const int* __restrict__ bbase,
                            int* __restrict__ row_ptr, int* __restrict__ ssrc, int N, int E) {
  __shared__ int h[LOCAL];
  __shared__ int sd[LOCAL];
  int b = blockIdx.x;
  int t = threadIdx.x;  // blockDim.x == LOCAL == 256
  int beg = bbase[b], end = bbase[b + 1];
  int node0 = b << LBITS;
  h[t] = 0;
  __syncthreads();
  for (int j = beg + t; j < end; j += blockDim.x) atomicAdd(&h[packed[j] & (LOCAL - 1)], 1);
  __syncthreads();
  int cnt = h[t];
  sd[t] = cnt;
  __syncthreads();
  int acc = cnt;
  for (int off = 1; off < LOCAL; off <<= 1) {
    int u = (t >= off) ? sd[t - off] : 0;
    __syncthreads();
    acc += u;
    sd[t] = acc;
    __syncthreads();
  }
  int myex = acc - cnt;
  int node = node0 + t;
  if (node < N) row_ptr[node] = beg + myex;
  h[t] = beg + myex;
  if (b == gridDim.x - 1 && t == 0) row_ptr[N] = E;
  __syncthreads();
  for (int j = beg + t; j < end; j += blockDim.x) {
    int v = packed[j];
    int p = atomicAdd(&h[v & (LOCAL - 1)], 1);
    ssrc[p] = v >> LBITS;
  }
}

// ---------------- dense transforms: matrix-split (blockIdx.x % 3) ----------------
__global__ __launch_bounds__(256) void gemm3_128x16(
    const float* __restrict__ x, const float* __restrict__ Wl, const float* __restrict__ Wr,
    const float* __restrict__ Wlin, const float* __restrict__ blin,
    __hip_bfloat16* __restrict__ XLh, float* __restrict__ XR, float* __restrict__ SK, int N) {
  int bx = blockIdx.x;
  int mat = bx % 3;
  int node = (bx / 3) * 256 + threadIdx.x;
  if (node >= N) return;
  const float* __restrict__ W = (mat == 0) ? Wl : (mat == 1) ? Wr : Wlin;
  const float4* xr4 = (const float4*)(x + (size_t)node * F_IN);
  float acc[16];
#pragma unroll
  for (int c = 0; c < 16; c++) acc[c] = 0.f;
#pragma unroll 8
  for (int kk = 0; kk < F_IN / 4; kk++) {
    float4 xv = xr4[kk];
    float xs[4] = {xv.x, xv.y, xv.z, xv.w};
#pragma unroll
    for (int j = 0; j < 4; j++) {
      int k = kk * 4 + j;
#pragma unroll
      for (int c = 0; c < 16; c++) acc[c] = fmaf(xs[j], W[k * 16 + c], acc[c]);
    }
  }
  if (mat == 0) {
    unsigned int pk[8];
#pragma unroll
    for (int i = 0; i < 8; i++)
      pk[i] = (unsigned)f2bf(acc[2 * i]) | ((unsigned)f2bf(acc[2 * i + 1]) << 16);
    uint4* xlp = (uint4*)(XLh + (size_t)node * 16);
    xlp[0] = make_uint4(pk[0], pk[1], pk[2], pk[3]);
    xlp[1] = make_uint4(pk[4], pk[5], pk[6], pk[7]);
  } else if (mat == 1) {
    float4* xrp = (float4*)(XR + (size_t)node * 16);
#pragma unroll
    for (int q = 0; q < 4; q++)
      xrp[q] = make_float4(acc[4 * q], acc[4 * q + 1], acc[4 * q + 2], acc[4 * q + 3]);
  } else {
    float4* skp = (float4*)(SK + (size_t)node * 16);
#pragma unroll
    for (int q = 0; q < 4; q++)
      skp[q] = make_float4(acc[4 * q] + blin[4 * q], acc[4 * q + 1] + blin[4 * q + 1],
                           acc[4 * q + 2] + blin[4 * q + 2], acc[4 * q + 3] + blin[4 * q + 3]);
  }
}

// ---------------- GAT layer: 4-phase; FUSEG2 epilogue emits layer-2 transforms; HEAD emits MLP ----------------
template <int C, int POOL, bool HEAD, bool FUSEG2>
__global__ __launch_bounds__(256) void gat_layer(
    const __hip_bfloat16* __restrict__ XLh, const float* __restrict__ XR,
    const float* __restrict__ SK, const float* __restrict__ att, const float* __restrict__ bias,
    const float* __restrict__ tp, const int* __restrict__ row_ptr, const int* __restrict__ ssrc,
    float* __restrict__ H, int N,
    const float* __restrict__ P0, const float* __restrict__ P1, const float* __restrict__ P2,
    const float* __restrict__ P3, const float* __restrict__ P4, const float* __restrict__ P5,
    const float* __restrict__ P6, const float* __restrict__ P7,
    __hip_bfloat16* __restrict__ XL2h, float* __restrict__ XR2, float* __restrict__ SK2,
    float* __restrict__ out) {
  constexpr int NPB = 256 / C;
  constexpr int LOGNPB = (NPB == 16) ? 4 : 5;
  __shared__ __align__(16) unsigned short vpool[POOL * C];
  __shared__ float ppool[POOL];
  __shared__ __align__(16) float xrl[NPB * C];
  __shared__ float invS0s[NPB];
  __shared__ int nb[NPB + 1];
  __shared__ float hsh[(HEAD || FUSEG2) ? NPB * C : 1];
  __shared__ float wfuse[FUSEG2 ? 392 : 1];
  int t = threadIdx.x;
  int node0 = blockIdx.x * NPB;

  if (t <= NPB) {
    int nd = node0 + t;
    nb[t] = row_ptr[(nd < N) ? nd : N];
  }
  {
    size_t xi = (size_t)node0 * C + t;
    xrl[t] = (xi < (size_t)N * C) ? XR[xi] : 0.f;
  }
  if constexpr (FUSEG2) {
    // P0=Wl2,P1=Wr2,P2=Wlin2,P3=blin2: [0,128)=Wl2,[128,256)=Wr2,[256,384)=Wlin2,[384,392)=blin2
    for (int i = t; i < 392; i += 256)
      wfuse[i] = (i < 128) ? P0[i] : (i < 256) ? P1[i - 128] : (i < 384) ? P2[i - 256] : P3[i - 384];
  }
  float attr[C];
#pragma unroll
  for (int cc = 0; cc < C; cc++) attr[cc] = att[cc];
  float tval = tp[0];
  __syncthreads();

  int bbeg = nb[0];
  int nE = nb[NPB] - bbeg;
  int nCap = (nE < POOL) ? nE : POOL;
  const unsigned short* XLu = (const unsigned short*)XLh;

  // ---- Phase S: edge-per-lane gather + score ----
  for (int slot = t; slot < nCap; slot += 256) {
    int sb = slot + bbeg;
    int lo = 0, hi = NPB;
#pragma unroll
    for (int st = 0; st < LOGNPB; st++) {
      int mid = (lo + hi) >> 1;
      bool go = nb[mid] <= sb;
      lo = go ? mid : lo;
      hi = go ? hi : mid;
    }
    int g = lo;
    int s = ssrc[sb];
    float v[C];
    if constexpr (C == 16) {
      const uint4* gp = (const uint4*)(XLu + (size_t)s * 16);
      uint4 a = gp[0], b = gp[1];
      *(uint4*)&vpool[slot * 16] = a;
      *(uint4*)&vpool[slot * 16 + 8] = b;
      unsigned arr[8] = {a.x, a.y, a.z, a.w, b.x, b.y, b.z, b.w};
#pragma unroll
      for (int i = 0; i < 8; i++) {
        v[2 * i] = __uint_as_float(arr[i] << 16);
        v[2 * i + 1] = __uint_as_float(arr[i] & 0xffff0000u);
      }
    } else {
      const uint4* gp = (const uint4*)(XLu + (size_t)s * 8);
      uint4 a = gp[0];
      *(uint4*)&vpool[slot * 8] = a;
      unsigned arr[4] = {a.x, a.y, a.z, a.w};
#pragma unroll
      for (int i = 0; i < 4; i++) {
        v[2 * i] = __uint_as_float(arr[i] << 16);
        v[2 * i + 1] = __uint_as_float(arr[i] & 0xffff0000u);
      }
    }
    float xr[C];
    const float4* xp = (const float4*)&xrl[g * C];
#pragma unroll
    for (int q = 0; q < C / 4; q++) {
      float4 f = xp[q];
      xr[4 * q] = f.x;
      xr[4 * q + 1] = f.y;
      xr[4 * q + 2] = f.z;
      xr[4 * q + 3] = f.w;
    }
    float p0 = 0.f, p1 = 0.f, p2 = 0.f, p3 = 0.f;
#pragma unroll
    for (int cc = 0; cc < C; cc += 4) {
      float u0 = v[cc] + xr[cc];
      float u1 = v[cc + 1] + xr[cc + 1];
      float u2 = v[cc + 2] + xr[cc + 2];
      float u3 = v[cc + 3] + xr[cc + 3];
      p0 = fmaf(fmaxf(u0, 0.2f * u0), attr[cc], p0);
      p1 = fmaf(fmaxf(u1, 0.2f * u1), attr[cc + 1], p1);
      p2 = fmaf(fmaxf(u2, 0.2f * u2), attr[cc + 2], p2);
      p3 = fmaf(fmaxf(u3, 0.2f * u3), attr[cc + 3], p3);
    }
    ppool[slot] = __expf((p0 + p1) + (p2 + p3));
  }
  __syncthreads();

  int g = t / C;
  int c = t % C;
  int base = nb[g] - bbeg;
  int deg = nb[g + 1] - nb[g];
  int capd = POOL - base;
  capd = capd < 0 ? 0 : (capd > deg ? deg : capd);

  // ---- Phase D: S0 per node ----
  {
    float s0 = 0.f;
    for (int j = c; j < capd; j += C) s0 += ppool[base + j];
    for (int j = capd + c; j < deg; j += C) {  // overflow fallback (~never)
      int s = ssrc[bbeg + base + j];
      float sc = 0.f;
#pragma unroll
      for (int cc = 0; cc < C; cc++) {
        float v = __bfloat162float(XLh[(size_t)s * C + cc]);
        float u = v + xrl[g * C + cc];
        sc = fmaf(fmaxf(u, 0.2f * u), attr[cc], sc);
      }
      s0 += __expf(sc);
    }
#pragma unroll
    for (int m = 1; m < C; m <<= 1) s0 += __shfl_xor(s0, m, C);
    if (c == 0) invS0s[g] = (deg > 0) ? 1.0f / s0 : 0.f;
  }
  __syncthreads();

  // ---- Phase 2: aggregation softmax (LDS-only, 2x unrolled) ----
  float invS0 = invS0s[g];
  float S1 = 0.f, S2 = 0.f, S1b = 0.f, S2b = 0.f;
  int jj = 0;
  for (; jj + 2 <= capd; jj += 2) {
    int sl0 = base + jj;
    float v0 = __uint_as_float(((unsigned)vpool[sl0 * C + c]) << 16);
    float p0 = ppool[sl0];
    float v1 = __uint_as_float(((unsigned)vpool[(sl0 + 1) * C + c]) << 16);
    float p1 = ppool[sl0 + 1];
    float m0 = v0 * (p0 * invS0);
    float m1 = v1 * (p1 * invS0);
    float w0 = __expf(m0 * tval);
    float w1 = __expf(m1 * tval);
    S1 += w0;
    S2 = fmaf(w0, m0, S2);
    S1b += w1;
    S2b = fmaf(w1, m1, S2b);
  }
  for (; jj < capd; jj++) {
    int sl = base + jj;
    float v = __uint_as_float(((unsigned)vpool[sl * C + c]) << 16);
    float p = ppool[sl];
    float mm = v * (p * invS0);
    float w = __expf(mm * tval);
    S1 += w;
    S2 = fmaf(w, mm, S2);
  }
  for (; jj < deg; jj++) {  // overflow fallback (~never)
    int s = ssrc[bbeg + base + jj];
    float sc = 0.f, vc = 0.f;
#pragma unroll
    for (int cc = 0; cc < C; cc++) {
      float v = __bfloat162float(XLh[(size_t)s * C + cc]);
      if (cc == c) vc = v;
      float u = v + xrl[g * C + cc];
      sc = fmaf(fmaxf(u, 0.2f * u), attr[cc], sc);
    }
    float p = __expf(sc);
    float mm = vc * (p * invS0);
    float w = __expf(mm * tval);
    S1 += w;
    S2 = fmaf(w, mm, S2);
  }
  S1 += S1b;
  S2 += S2b;

  int node = node0 + g;
  bool valid = node < N;
  float hval = 0.f;
  if (valid) {
    float gat = (deg > 0) ? (S2 / S1) : 0.f;
    hval = fmaxf(gat + bias[c] + SK[(size_t)node * C + c], 0.f);
  }
  if constexpr (FUSEG2) {
    hsh[g * C + c] = hval;
    __syncthreads();
    if (t < NPB * 8) {  // 16 nodes x 8 out-channels
      int g2 = t >> 3, c2 = t & 7;
      int nd = node0 + g2;
      if (nd < N) {
        float a0 = 0.f, a1 = 0.f, a2 = 0.f;
#pragma unroll
        for (int k = 0; k < 16; k++) {
          float hv = hsh[g2 * 16 + k];
          a0 = fmaf(hv, wfuse[k * 8 + c2], a0);
          a1 = fmaf(hv, wfuse[128 + k * 8 + c2], a1);
          a2 = fmaf(hv, wfuse[256 + k * 8 + c2], a2);
        }
        ((unsigned short*)XL2h)[(size_t)nd * 8 + c2] = f2bf(a0);
        XR2[(size_t)nd * 8 + c2] = a1;
        SK2[(size_t)nd * 8 + c2] = a2 + wfuse[384 + c2];
      }
    }
  } else if constexpr (HEAD) {
    hsh[g * C + c] = hval;
    __syncthreads();
    if (t < NPB) {
      int nd = node0 + t;
      if (nd < N) {
        float h[8];
#pragma unroll
        for (int k = 0; k < 8; k++) h[k] = hsh[t * 8 + k];
        float s4 = 0.f;
#pragma unroll
        for (int cc = 0; cc < 8; cc++) {
          float z = P1[cc];  // b3
#pragma unroll
          for (int k = 0; k < 8; k++) z = fmaf(h[k], P0[k * 8 + cc], z);  // W3
          z = fmaxf(z, 0.f);
          s4 = fmaf(z, P2[cc], s4);  // W4
        }
        s4 = fmaxf(s4 + P3[0], 0.f);                    // b4
        float s5 = fmaxf(fmaf(s4, P4[0], P5[0]), 0.f);  // W5,b5
        float zo = fmaf(s5, P6[0], P7[0]);              // Wout,bout
        float ls;
        if (zo >= 0.f)
          ls = -log1pf(expf(-zo));
        else
          ls = zo - log1pf(expf(zo));
        out[nd] = ls;
      }
    }
  } else {
    if (valid) H[(size_t)node * C + c] = hval;
  }
}

extern "C" void kernel_launch(void* const* d_in, const int* in_sizes, int n_in,
                              void* d_out, int out_size, void* d_ws, size_t ws_size,
                              hipStream_t stream) {
  const float* x = (const float*)d_in[0];
  const int* ei = (const int*)d_in[1];
  const float* Wl1 = (const float*)d_in[3];
  const float* Wr1 = (const float*)d_in[4];
  const float* att1 = (const float*)d_in[5];
  const float* b1 = (const float*)d_in[6];
  const float* Wlin1 = (const float*)d_in[7];
  const float* blin1 = (const float*)d_in[8];
  const float* Wl2 = (const float*)d_in[9];
  const float* Wr2 = (const float*)d_in[10];
  const float* att2 = (const float*)d_in[11];
  const float* b2 = (const float*)d_in[12];
  const float* Wlin2 = (const float*)d_in[13];
  const float* blin2 = (const float*)d_in[14];
  const float* t = (const float*)d_in[15];
  const float* W3 = (const float*)d_in[16];
  const float* b3 = (const float*)d_in[17];
  const float* W4 = (const float*)d_in[18];
  const float* b4 = (const float*)d_in[19];
  const float* W5 = (const float*)d_in[20];
  const float* b5 = (const float*)d_in[21];
  const float* Wout = (const float*)d_in[22];
  const float* bout = (const float*)d_in[23];
  float* out = (float*)d_out;

  int N = in_sizes[0] / F_IN;
  int E = in_sizes[1] / 2;
  const int* src = ei;
  const int* dst = ei + E;
  int NB = (N + LOCAL - 1) >> LBITS;  // 391 for N=100000

  char* ws = (char*)d_ws;
  size_t off = 0;
  auto alloc = [&](size_t bytes) -> void* {
    void* p = ws + off;
    off = (off + bytes + 255) & ~(size_t)255;
    return p;
  };
  int* bcount = (int*)alloc((size_t)NB * 4);
  int* bbase = (int*)alloc((size_t)(NB + 1) * 4);
  int* bcursor = (int*)alloc((size_t)NB * 4);
  int* packed = (int*)alloc((size_t)E * 4);
  int* row_ptr = (int*)alloc((size_t)(N + 1) * 4);
  int* ssrc = (int*)alloc((size_t)E * 4);
  __hip_bfloat16* XL1 = (__hip_bfloat16*)alloc((size_t)N * C1 * 2);
  float* XR1 = (float*)alloc((size_t)N * C1 * 4);
  float* SK1 = (float*)alloc((size_t)N * C1 * 4);
  __hip_bfloat16* XL2 = (__hip_bfloat16*)alloc((size_t)N * C2 * 2);
  float* XR2 = (float*)alloc((size_t)N * C2 * 4);
  float* SK2 = (float*)alloc((size_t)N * C2 * 4);

  int nblkA = (E + EPB - 1) / EPB;
  int nodeBlk = (N + 255) / 256;  // 391

  hipMemsetAsync(bcount, 0, (size_t)NB * 4, stream);
  hipLaunchKernelGGL(bucket_hist, dim3(512), dim3(256), 0, stream, dst, bcount, E, NB);
  hipLaunchKernelGGL(bucket_scan, dim3(1), dim3(NB_MAX), 0, stream, bcount, bbase, bcursor, NB);
  hipLaunchKernelGGL(phaseA_lds, dim3(nblkA), dim3(256), 0, stream, src, dst, bcursor, packed, E,
                     NB);
  hipLaunchKernelGGL(phaseB_sort, dim3(NB), dim3(LOCAL), 0, stream, packed, bbase, row_ptr, ssrc, N,
                     E);
  hipLaunchKernelGGL(gemm3_128x16, dim3(nodeBlk * 3), dim3(256), 0, stream, x, Wl1, Wr1,
                     Wlin1, blin1, XL1, XR1, SK1, N);
  hipLaunchKernelGGL((gat_layer<16, 640, false, true>), dim3((N + 15) / 16), dim3(256), 0, stream,
                     XL1, XR1, SK1, att1, b1, t, row_ptr, ssrc, nullptr, N, Wl2, Wr2, Wlin2, blin2,
                     nullptr, nullptr, nullptr, nullptr, XL2, XR2, SK2, nullptr);
  hipLaunchKernelGGL((gat_layer<8, 1280, true, false>), dim3((N + 31) / 32), dim3(256), 0, stream,
                     XL2, XR2, SK2, att2, b2, t, row_ptr, ssrc, nullptr, N, W3, b3, W4, b4, W5, b5,
                     Wout, bout, nullptr, nullptr, nullptr, out);
}